// Round 12
// baseline (278.210 us; speedup 1.0000x reference)
//
#include <hip/hip_runtime.h>
#include <hip/hip_bf16.h>

// GraphSAGE (2x SAGEConv mean + normalize + relu, final linear) on MI355X.
// R12: partitionB_fused was 81us at 34% occupancy — 115KB LDS forced 1
// block/CU, serializing its barrier-separated phases. Now each 256-node bucket
// is processed by TWO half-bucket blocks (128 nodes each, grid 391->782): each
// reads the whole bucket's part region but filters on dstLocal>>7, cutting LDS
// to ~63KB -> 2 blocks/CU -> cross-phase overlap. partitionA untouched.

#define CHA 16384   // edges per phase-A block
#define MAXB 512    // max coarse buckets (NB = ceil(N/256) = 391)
#define CAPB 18432  // part slots per 256-node bucket region
#define CAPH 9728   // sorted_src slots per 128-node half-bucket region
#define NPB 128     // nodes per dense block

static __device__ __forceinline__ unsigned short f2bf(float f) {
    unsigned u = __float_as_uint(f);
    unsigned r = (u + 0x7FFFu + ((u >> 16) & 1u)) >> 16;   // RTN-even
    return (unsigned short)r;
}
#define BF_LO(u) __uint_as_float((u) << 16)
#define BF_HI(u) __uint_as_float((u) & 0xFFFF0000u)

// x [N x 14] fp32 -> xb [N x 16] bf16 (rows padded to 32B). Also inits bcursor.
__global__ void cvt_x_bf16(const float* __restrict__ x, unsigned short* __restrict__ xb,
                           int* __restrict__ bcursor, int N, int NB) {
    int idx = blockIdx.x * blockDim.x + threadIdx.x;
    if (idx < NB) bcursor[idx] = idx * CAPB;
    if (idx >= N * 16) return;
    int n = idx >> 4, f = idx & 15;
    float v = (f < 14) ? x[n * 14 + f] : 0.f;
    xb[idx] = f2bf(v);
}

// Phase A: per-block counting sort into LDS, coalesced per-run copy-out into
// the slack bucket regions. dst/src loaded ONCE as int4 into registers.
__global__ __launch_bounds__(1024) void partitionA(
        const int* __restrict__ src, const int* __restrict__ dst,
        int* __restrict__ bcursor, unsigned* __restrict__ part, int E, int NB) {
    __shared__ unsigned pk[CHA];                       // 64 KB staging
    __shared__ int h[MAXB], lofs[MAXB], cur[MAXB], delta[MAXB], tmp[MAXB];
    int t = threadIdx.x;
    int base = blockIdx.x * CHA;
    int end = base + CHA; if (end > E) end = E;
    int cnt = end - base;

    int ed[16], es[16];
    for (int i = t; i < NB; i += 1024) h[i] = 0;
    __syncthreads();
    #pragma unroll
    for (int i = 0; i < 4; ++i) {
        int j = i * 4096 + t * 4;
        if (j + 4 <= cnt) {
            int4 d4 = *(const int4*)(dst + base + j);
            int4 s4 = *(const int4*)(src + base + j);
            ed[i*4+0] = d4.x; ed[i*4+1] = d4.y; ed[i*4+2] = d4.z; ed[i*4+3] = d4.w;
            es[i*4+0] = s4.x; es[i*4+1] = s4.y; es[i*4+2] = s4.z; es[i*4+3] = s4.w;
            atomicAdd(&h[d4.x >> 8], 1);
            atomicAdd(&h[d4.y >> 8], 1);
            atomicAdd(&h[d4.z >> 8], 1);
            atomicAdd(&h[d4.w >> 8], 1);
        } else {
            #pragma unroll
            for (int k = 0; k < 4; ++k) {
                if (j + k < cnt) {
                    ed[i*4+k] = dst[base + j + k];
                    es[i*4+k] = src[base + j + k];
                    atomicAdd(&h[ed[i*4+k] >> 8], 1);
                } else ed[i*4+k] = -1;
            }
        }
    }
    __syncthreads();
    int v = 0;
    if (t < MAXB) { v = (t < NB) ? h[t] : 0; tmp[t] = v; }
    __syncthreads();
    for (int off = 1; off < MAXB; off <<= 1) {
        int a = 0;
        if (t < MAXB && t >= off) a = tmp[t - off];
        __syncthreads();
        if (t < MAXB) tmp[t] += a;
        __syncthreads();
    }
    if (t < NB) {
        int excl = tmp[t] - v;
        lofs[t] = excl;
        cur[t] = excl;
        int g = v ? atomicAdd(&bcursor[t], v) : 0;   // reserve run in slack region
        delta[t] = g - excl;
    }
    __syncthreads();
    #pragma unroll
    for (int i = 0; i < 16; ++i) {
        int d = ed[i];
        if (d >= 0) {
            int b = d >> 8;
            int r = atomicAdd(&cur[b], 1);
            pk[r] = ((unsigned)(d & 255) << 24) | (unsigned)es[i];
        }
    }
    __syncthreads();
    int wid = t >> 6, lane = t & 63;
    for (int b = wid; b < NB; b += 16) {
        int s = lofs[b];
        int e2 = (b + 1 < NB) ? lofs[b + 1] : cnt;
        int dlt = delta[b];
        int lim = (b + 1) * CAPB;                    // overflow guard (never hit)
        for (int k = s + lane; k < e2; k += 64) {
            int gidx = dlt + k;
            if (gidx < lim) part[gidx] = pk[k];
        }
    }
}

// Phase B fused, half-bucket: block = (bucket b, half) handles 128 dst nodes.
// Reads the bucket's whole part region (register-cached) filtering on
// dstLocal>>7; 256-key counting sort (key = (dstLocal&127)*2 + (src>=HALF)) in
// LDS; sorted_src written to its own CAPH region; then fused LAYER-1 GATHER
// (8 thr/node = 4 edge-streams x 2 row-halves) + DENSE1 (+norm+relu).
__global__ __launch_bounds__(1024) void partitionB_fused(
        const unsigned* __restrict__ part, const int* __restrict__ bcursor,
        const uint4* __restrict__ xb4, const float* __restrict__ x,
        const float* __restrict__ W1l, const float* __restrict__ b1,
        const float* __restrict__ W1r,
        int* __restrict__ deg, int* __restrict__ offs, int* __restrict__ nlo,
        int* __restrict__ sorted_src, float* __restrict__ hbuf,
        unsigned short* __restrict__ hb, int N, int HALF) {
    __shared__ int pk2[CAPH];                          // 38 KB staging
    __shared__ int hh[256], tmp[256], keyofs[256];
    __shared__ int lstart[128], ldeg[128];
    __shared__ float sagg[128 * 17];                   // agg1 sums, stride 17
    __shared__ float sx[128 * 14];                     // x rows
    __shared__ float swl[448], swr[448], sb1[32];
    __shared__ int sTot;
    int b = blockIdx.x >> 1;
    int halfId = blockIdx.x & 1;
    int t = threadIdx.x;
    int start = b * CAPB;
    int end = bcursor[b];
    if (end > start + CAPB) end = start + CAPB;
    int rbase = blockIdx.x * CAPH;                     // this half's output region
    unsigned ce[18];
    if (t < 256) hh[t] = 0;
    if (t >= 512 && t < 960) { swl[t - 512] = W1l[t - 512]; swr[t - 512] = W1r[t - 512]; }
    else if (t >= 960 && t < 992) sb1[t - 960] = b1[t - 960];
    __syncthreads();
    #pragma unroll
    for (int i = 0; i < 18; ++i) {
        int idx = start + t + i * 1024;
        unsigned p = 0xFFFFFFFFu;
        if (idx < end) {
            p = part[idx];
            int dl = (int)(p >> 24);
            if ((dl >> 7) == halfId) {
                int key = (dl & 127) * 2 + (((int)(p & 0xFFFFFFu) < HALF) ? 0 : 1);
                atomicAdd(&hh[key], 1);
            } else p = 0xFFFFFFFFu;
        }
        ce[i] = p;
    }
    {   // stage x rows for this half-bucket
        int nbase = b * 256 + halfId * 128;
        int nnod = N - nbase; if (nnod > 128) nnod = 128; if (nnod < 0) nnod = 0;
        const float* gx = x + (size_t)nbase * 14;
        for (int i = t; i < nnod * 14; i += 1024) sx[i] = gx[i];
    }
    __syncthreads();
    int v = (t < 256) ? hh[t] : 0;
    if (t < 256) tmp[t] = v;
    __syncthreads();
    for (int off = 1; off < 256; off <<= 1) {
        int a2 = (t < 256 && t >= off) ? tmp[t - off] : 0;
        __syncthreads();
        if (t < 256) tmp[t] += a2;
        __syncthreads();
    }
    if (t < 256) keyofs[t] = tmp[t] - v;               // exclusive per key
    if (t == 255) sTot = tmp[255];
    __syncthreads();
    if (t < 128) {
        int lo = hh[2 * t];
        int d = lo + hh[2 * t + 1];
        int excl = keyofs[2 * t];
        lstart[t] = excl;
        ldeg[t] = d;
        int node = b * 256 + halfId * 128 + t;
        if (node < N) {
            deg[node] = d;
            offs[node] = rbase + excl;
            nlo[node] = lo;
        }
    }
    __syncthreads();
    #pragma unroll
    for (int i = 0; i < 18; ++i) {
        unsigned p = ce[i];
        if (p != 0xFFFFFFFFu) {
            int s = (int)(p & 0xFFFFFFu);
            int dl = (int)(p >> 24);
            int key = (dl & 127) * 2 + ((s < HALF) ? 0 : 1);
            int r = atomicAdd(&keyofs[key], 1);
            if (r < CAPH) pk2[r] = s;
        }
    }
    __syncthreads();
    int tot = sTot; if (tot > CAPH) tot = CAPH;
    for (int i = t; i < tot; i += 1024)
        sorted_src[rbase + i] = pk2[i];

    // ---- fused layer-1 gather: 8 threads/node = 4 edge-streams x 2 row-halves
    int node = t >> 3, sub = t & 7, ep = sub >> 1, half = sub & 1;
    int js = lstart[node], d = ldeg[node];
    int je = js + d;
    float a[8] = {0,0,0,0,0,0,0,0};
    int j = js + ep;
    for (; j + 4 < je; j += 8) {                      // 2 edges/iter per stream
        int s0 = pk2[j], s1 = pk2[j + 4];
        uint4 u0 = xb4[s0 * 2 + half], u1 = xb4[s1 * 2 + half];
        a[0] += BF_LO(u0.x) + BF_LO(u1.x);
        a[1] += BF_HI(u0.x) + BF_HI(u1.x);
        a[2] += BF_LO(u0.y) + BF_LO(u1.y);
        a[3] += BF_HI(u0.y) + BF_HI(u1.y);
        a[4] += BF_LO(u0.z) + BF_LO(u1.z);
        a[5] += BF_HI(u0.z) + BF_HI(u1.z);
        a[6] += BF_LO(u0.w) + BF_LO(u1.w);
        a[7] += BF_HI(u0.w) + BF_HI(u1.w);
    }
    for (; j < je; j += 4) {
        uint4 u0 = xb4[pk2[j] * 2 + half];
        a[0] += BF_LO(u0.x); a[1] += BF_HI(u0.x);
        a[2] += BF_LO(u0.y); a[3] += BF_HI(u0.y);
        a[4] += BF_LO(u0.z); a[5] += BF_HI(u0.z);
        a[6] += BF_LO(u0.w); a[7] += BF_HI(u0.w);
    }
    #pragma unroll
    for (int i = 0; i < 8; ++i) {
        a[i] += __shfl_xor(a[i], 2);                  // merge stream pairs
        a[i] += __shfl_xor(a[i], 4);                  // merge all 4 streams
    }
    if (ep == 0) {                                     // sub in {0,1}: both halves
        #pragma unroll
        for (int i = 0; i < 8; ++i) sagg[node * 17 + half * 8 + i] = a[i];
    }
    __syncthreads();

    // ---- fused dense1: 8 threads/node, each computes 4 of 32 outputs
    float inv = 1.0f / ((d > 0) ? (float)d : 1.0f);
    float acc[4];
    #pragma unroll
    for (int i = 0; i < 4; ++i) acc[i] = sb1[sub * 4 + i];
    #pragma unroll
    for (int k = 0; k < 14; ++k) {
        float ag = sagg[node * 17 + k] * inv;
        float xv = sx[node * 14 + k];
        float4 wl = *(const float4*)&swl[k * 32 + sub * 4];
        float4 wr = *(const float4*)&swr[k * 32 + sub * 4];
        acc[0] += ag * wl.x + xv * wr.x;
        acc[1] += ag * wl.y + xv * wr.y;
        acc[2] += ag * wl.z + xv * wr.z;
        acc[3] += ag * wl.w + xv * wr.w;
    }
    float ss = 0.f;
    #pragma unroll
    for (int i = 0; i < 4; ++i) ss += acc[i] * acc[i];
    ss += __shfl_xor(ss, 1); ss += __shfl_xor(ss, 2); ss += __shfl_xor(ss, 4);
    float invn = 1.f / fmaxf(sqrtf(ss), 1e-12f);
    int gnode = b * 256 + halfId * 128 + node;
    if (gnode < N) {
        float hv[4];
        #pragma unroll
        for (int i = 0; i < 4; ++i) hv[i] = fmaxf(acc[i] * invn, 0.f);
        *(float4*)(hbuf + (size_t)gnode * 32 + sub * 4) =
            make_float4(hv[0], hv[1], hv[2], hv[3]);
        uint2 pb;
        pb.x = (unsigned)f2bf(hv[0]) | ((unsigned)f2bf(hv[1]) << 16);
        pb.y = (unsigned)f2bf(hv[2]) | ((unsigned)f2bf(hv[3]) << 16);
        *(uint2*)(hb + (size_t)gnode * 32 + sub * 4) = pb;
    }
}

// Layer-2 gather pass 0 (src < HALF; table half 3.2MB bf16, L2-resident).
__global__ void gather32_p0(const uint4* __restrict__ hb, const int* __restrict__ sorted_src,
                            const int* __restrict__ offs, const int* __restrict__ nlo,
                            float4* __restrict__ agg2, int N) {
    int idx = blockIdx.x * blockDim.x + threadIdx.x;
    int n = idx >> 2;
    if (n >= N) return;
    int q = idx & 3;
    int start = offs[n];
    int jend = nlo[n];
    float a0=0,a1=0,a2=0,a3=0,a4=0,a5=0,a6=0,a7=0;
    int j = 0;
    for (; j + 4 <= jend; j += 4) {
        int s0 = sorted_src[start + j + 0];
        int s1 = sorted_src[start + j + 1];
        int s2 = sorted_src[start + j + 2];
        int s3 = sorted_src[start + j + 3];
        uint4 u0 = hb[s0 * 4 + q];
        uint4 u1 = hb[s1 * 4 + q];
        uint4 u2 = hb[s2 * 4 + q];
        uint4 u3 = hb[s3 * 4 + q];
        a0 += BF_LO(u0.x) + BF_LO(u1.x) + BF_LO(u2.x) + BF_LO(u3.x);
        a1 += BF_HI(u0.x) + BF_HI(u1.x) + BF_HI(u2.x) + BF_HI(u3.x);
        a2 += BF_LO(u0.y) + BF_LO(u1.y) + BF_LO(u2.y) + BF_LO(u3.y);
        a3 += BF_HI(u0.y) + BF_HI(u1.y) + BF_HI(u2.y) + BF_HI(u3.y);
        a4 += BF_LO(u0.z) + BF_LO(u1.z) + BF_LO(u2.z) + BF_LO(u3.z);
        a5 += BF_HI(u0.z) + BF_HI(u1.z) + BF_HI(u2.z) + BF_HI(u3.z);
        a6 += BF_LO(u0.w) + BF_LO(u1.w) + BF_LO(u2.w) + BF_LO(u3.w);
        a7 += BF_HI(u0.w) + BF_HI(u1.w) + BF_HI(u2.w) + BF_HI(u3.w);
    }
    for (; j < jend; ++j) {
        uint4 u0 = hb[sorted_src[start + j] * 4 + q];
        a0 += BF_LO(u0.x); a1 += BF_HI(u0.x);
        a2 += BF_LO(u0.y); a3 += BF_HI(u0.y);
        a4 += BF_LO(u0.z); a5 += BF_HI(u0.z);
        a6 += BF_LO(u0.w); a7 += BF_HI(u0.w);
    }
    agg2[n * 8 + q * 2 + 0] = make_float4(a0, a1, a2, a3);
    agg2[n * 8 + q * 2 + 1] = make_float4(a4, a5, a6, a7);
}

// Layer-2 gather pass 1 (src >= HALF): adds to pass-0 sums, applies 1/deg.
__global__ void gather32_p1(const uint4* __restrict__ hb, const int* __restrict__ sorted_src,
                            const int* __restrict__ offs, const int* __restrict__ deg,
                            const int* __restrict__ nlo, float4* __restrict__ agg2, int N) {
    int idx = blockIdx.x * blockDim.x + threadIdx.x;
    int n = idx >> 2;
    if (n >= N) return;
    int q = idx & 3;
    int start = offs[n];
    int d = deg[n];
    int j = nlo[n];
    float a0=0,a1=0,a2=0,a3=0,a4=0,a5=0,a6=0,a7=0;
    for (; j + 4 <= d; j += 4) {
        int s0 = sorted_src[start + j + 0];
        int s1 = sorted_src[start + j + 1];
        int s2 = sorted_src[start + j + 2];
        int s3 = sorted_src[start + j + 3];
        uint4 u0 = hb[s0 * 4 + q];
        uint4 u1 = hb[s1 * 4 + q];
        uint4 u2 = hb[s2 * 4 + q];
        uint4 u3 = hb[s3 * 4 + q];
        a0 += BF_LO(u0.x) + BF_LO(u1.x) + BF_LO(u2.x) + BF_LO(u3.x);
        a1 += BF_HI(u0.x) + BF_HI(u1.x) + BF_HI(u2.x) + BF_HI(u3.x);
        a2 += BF_LO(u0.y) + BF_LO(u1.y) + BF_LO(u2.y) + BF_LO(u3.y);
        a3 += BF_HI(u0.y) + BF_HI(u1.y) + BF_HI(u2.y) + BF_HI(u3.y);
        a4 += BF_LO(u0.z) + BF_LO(u1.z) + BF_LO(u2.z) + BF_LO(u3.z);
        a5 += BF_HI(u0.z) + BF_HI(u1.z) + BF_HI(u2.z) + BF_HI(u3.z);
        a6 += BF_LO(u0.w) + BF_LO(u1.w) + BF_LO(u2.w) + BF_LO(u3.w);
        a7 += BF_HI(u0.w) + BF_HI(u1.w) + BF_HI(u2.w) + BF_HI(u3.w);
    }
    for (; j < d; ++j) {
        uint4 u0 = hb[sorted_src[start + j] * 4 + q];
        a0 += BF_LO(u0.x); a1 += BF_HI(u0.x);
        a2 += BF_LO(u0.y); a3 += BF_HI(u0.y);
        a4 += BF_LO(u0.z); a5 += BF_HI(u0.z);
        a6 += BF_LO(u0.w); a7 += BF_HI(u0.w);
    }
    float inv = 1.0f / ((d > 0) ? (float)d : 1.0f);
    float4 p0 = agg2[n * 8 + q * 2 + 0];
    float4 p1 = agg2[n * 8 + q * 2 + 1];
    agg2[n * 8 + q * 2 + 0] = make_float4((p0.x + a0) * inv, (p0.y + a1) * inv,
                                          (p0.z + a2) * inv, (p0.w + a3) * inv);
    agg2[n * 8 + q * 2 + 1] = make_float4((p1.x + a4) * inv, (p1.y + a5) * inv,
                                          (p1.z + a6) * inv, (p1.w + a7) * inv);
}

// Layer 2 + final linear, tiled (conflict-free padded strides, VGPR ~36).
__global__ __launch_bounds__(256) void dense2(
        const float* __restrict__ h, const float* __restrict__ agg2,
        const float* __restrict__ W2l, const float* __restrict__ b2,
        const float* __restrict__ W2r, const float* __restrict__ Wlin,
        const float* __restrict__ blin, float* __restrict__ out, int N) {
    __shared__ float sa[NPB * 33];
    __shared__ float sh2[NPB * 33];
    __shared__ float swl[32 * 32], swr[32 * 32], swo[64], sb[32], sbo[2];
    int t = threadIdx.x;
    int nb = blockIdx.x * NPB;
    int nn = N - nb; if (nn > NPB) nn = NPB;
    const float4* ga = (const float4*)(agg2 + (size_t)nb * 32);
    const float4* gh = (const float4*)(h + (size_t)nb * 32);
    for (int i = t; i < nn * 8; i += 256) {
        float4 v = ga[i];
        float* d = &sa[(i >> 3) * 33 + (i & 7) * 4];
        d[0] = v.x; d[1] = v.y; d[2] = v.z; d[3] = v.w;
        float4 w = gh[i];
        float* e = &sh2[(i >> 3) * 33 + (i & 7) * 4];
        e[0] = w.x; e[1] = w.y; e[2] = w.z; e[3] = w.w;
    }
    for (int i = t; i < 1024; i += 256) { swl[i] = W2l[i]; swr[i] = W2r[i]; }
    if (t < 64) swo[t] = Wlin[t];
    if (t < 32) sb[t] = b2[t];
    if (t < 2) sbo[t] = blin[t];
    __syncthreads();
    int q2 = t & 3;
    int p = t >> 2;
    int l0 = p * 2, l1 = l0 + 1;
    float acc0[8], acc1[8];
    #pragma unroll
    for (int j = 0; j < 8; ++j) { acc0[j] = sb[q2 * 8 + j]; acc1[j] = acc0[j]; }
    for (int k = 0; k < 32; ++k) {
        float a0 = sa[l0 * 33 + k],  a1 = sa[l1 * 33 + k];
        float h0 = sh2[l0 * 33 + k], h1 = sh2[l1 * 33 + k];
        const float4* wl4 = (const float4*)&swl[k * 32 + q2 * 8];
        const float4* wr4 = (const float4*)&swr[k * 32 + q2 * 8];
        float4 wla = wl4[0], wlb = wl4[1], wra = wr4[0], wrb = wr4[1];
        acc0[0] += a0 * wla.x + h0 * wra.x;  acc1[0] += a1 * wla.x + h1 * wra.x;
        acc0[1] += a0 * wla.y + h0 * wra.y;  acc1[1] += a1 * wla.y + h1 * wra.y;
        acc0[2] += a0 * wla.z + h0 * wra.z;  acc1[2] += a1 * wla.z + h1 * wra.z;
        acc0[3] += a0 * wla.w + h0 * wra.w;  acc1[3] += a1 * wla.w + h1 * wra.w;
        acc0[4] += a0 * wlb.x + h0 * wrb.x;  acc1[4] += a1 * wlb.x + h1 * wrb.x;
        acc0[5] += a0 * wlb.y + h0 * wrb.y;  acc1[5] += a1 * wlb.y + h1 * wrb.y;
        acc0[6] += a0 * wlb.z + h0 * wrb.z;  acc1[6] += a1 * wlb.z + h1 * wrb.z;
        acc0[7] += a0 * wlb.w + h0 * wrb.w;  acc1[7] += a1 * wlb.w + h1 * wrb.w;
    }
    float ss0 = 0.f, ss1 = 0.f;
    #pragma unroll
    for (int j = 0; j < 8; ++j) { ss0 += acc0[j] * acc0[j]; ss1 += acc1[j] * acc1[j]; }
    ss0 += __shfl_xor(ss0, 1); ss0 += __shfl_xor(ss0, 2);
    ss1 += __shfl_xor(ss1, 1); ss1 += __shfl_xor(ss1, 2);
    float inv0 = 1.f / fmaxf(sqrtf(ss0), 1e-12f);
    float inv1 = 1.f / fmaxf(sqrtf(ss1), 1e-12f);
    float o00 = 0.f, o01 = 0.f, o10 = 0.f, o11 = 0.f;
    #pragma unroll
    for (int j = 0; j < 8; ++j) {
        float hv0 = fmaxf(acc0[j] * inv0, 0.f);
        float hv1 = fmaxf(acc1[j] * inv1, 0.f);
        int kk = q2 * 8 + j;
        o00 += hv0 * swo[kk * 2 + 0];
        o01 += hv0 * swo[kk * 2 + 1];
        o10 += hv1 * swo[kk * 2 + 0];
        o11 += hv1 * swo[kk * 2 + 1];
    }
    o00 += __shfl_xor(o00, 1); o00 += __shfl_xor(o00, 2);
    o01 += __shfl_xor(o01, 1); o01 += __shfl_xor(o01, 2);
    o10 += __shfl_xor(o10, 1); o10 += __shfl_xor(o10, 2);
    o11 += __shfl_xor(o11, 1); o11 += __shfl_xor(o11, 2);
    if (q2 == 0) {
        int n0 = nb + l0, n1 = nb + l1;
        if (n0 < N) { out[n0 * 2 + 0] = o00 + sbo[0]; out[n0 * 2 + 1] = o01 + sbo[1]; }
        if (n1 < N) { out[n1 * 2 + 0] = o10 + sbo[0]; out[n1 * 2 + 1] = o11 + sbo[1]; }
    }
}

extern "C" void kernel_launch(void* const* d_in, const int* in_sizes, int n_in,
                              void* d_out, int out_size, void* d_ws, size_t ws_size,
                              hipStream_t stream) {
    const float* x    = (const float*)d_in[0];
    const int*   ei   = (const int*)d_in[1];
    const float* W1l  = (const float*)d_in[2];
    const float* b1   = (const float*)d_in[3];
    const float* W1r  = (const float*)d_in[4];
    const float* W2l  = (const float*)d_in[5];
    const float* b2   = (const float*)d_in[6];
    const float* W2r  = (const float*)d_in[7];
    const float* Wlin = (const float*)d_in[8];
    const float* blin = (const float*)d_in[9];
    float* out = (float*)d_out;

    const int N = in_sizes[0] / 14;
    const int E = in_sizes[1] / 2;
    const int* src = ei;
    const int* dst = ei + E;
    const int NB = (N + 255) / 256;   // 391 coarse buckets
    const int HALF = N / 2;

    char* ws = (char*)d_ws;
    size_t off = 0;
    auto alloc = [&](size_t bytes) -> void* {
        void* p = ws + off;
        off = (off + bytes + 255) & ~(size_t)255;
        return p;
    };
    int*            bcursor    = (int*)alloc((size_t)NB * 4);
    unsigned*       part       = (unsigned*)alloc((size_t)NB * CAPB * 4);      // dead after partitionB
    int*            sorted_src = (int*)alloc((size_t)NB * 2 * CAPH * 4);       // half-bucket slack
    int*            deg        = (int*)alloc((size_t)N * 4);
    int*            offs       = (int*)alloc((size_t)N * 4);
    int*            nlo        = (int*)alloc((size_t)N * 4);
    unsigned short* xb         = (unsigned short*)alloc((size_t)N * 16 * 2);
    float*          hbuf       = (float*)alloc((size_t)N * 32 * 4);
    unsigned short* hb         = (unsigned short*)alloc((size_t)N * 32 * 2);
    float*          agg2       = (float*)part;                                 // alias dead part buffer
    (void)ws_size; (void)n_in; (void)out_size;

    cvt_x_bf16<<<(N * 16 + 255) / 256, 256, 0, stream>>>(x, xb, bcursor, N, NB);
    partitionA<<<(E + CHA - 1) / CHA, 1024, 0, stream>>>(src, dst, bcursor, part, E, NB);
    partitionB_fused<<<NB * 2, 1024, 0, stream>>>(
        part, bcursor, (const uint4*)xb, x, W1l, b1, W1r,
        deg, offs, nlo, sorted_src, hbuf, hb, N, HALF);
    gather32_p0<<<(N * 4 + 255) / 256, 256, 0, stream>>>(
        (const uint4*)hb, sorted_src, offs, nlo, (float4*)agg2, N);
    gather32_p1<<<(N * 4 + 255) / 256, 256, 0, stream>>>(
        (const uint4*)hb, sorted_src, offs, deg, nlo, (float4*)agg2, N);
    dense2<<<(N + NPB - 1) / NPB, 256, 0, stream>>>(
        hbuf, agg2, W2l, b2, W2r, Wlin, blin, out, N);
}

// Round 13
// 276.150 us; speedup vs baseline: 1.0075x; 1.0075x over previous
//
#include <hip/hip_runtime.h>
#include <hip/hip_bf16.h>

// GraphSAGE (2x SAGEConv mean + normalize + relu, final linear) on MI355X.
// R13: R12's half-bucket partitionB blocks each re-read the WHOLE 256-node
// bucket and filtered (FETCH 40->55MB, 2x histo work). partitionA now keys
// directly on 782 half-buckets (dst>>7); each partitionB block reads only its
// own ~8.2K-edge region. partitionA's scan runs in place over h (no tmp) to
// keep LDS at 76.5KB -> 2 blocks/CU.

#define CHA 16384   // edges per phase-A block
#define MAXBH 800   // max half-buckets (NBH = ceil(N/128) = 782)
#define CAPH 9728   // slots per 128-node half-bucket region (mean ~8.2K, ~17 sigma)
#define NPB 128     // nodes per dense block

static __device__ __forceinline__ unsigned short f2bf(float f) {
    unsigned u = __float_as_uint(f);
    unsigned r = (u + 0x7FFFu + ((u >> 16) & 1u)) >> 16;   // RTN-even
    return (unsigned short)r;
}
#define BF_LO(u) __uint_as_float((u) << 16)
#define BF_HI(u) __uint_as_float((u) & 0xFFFF0000u)

// x [N x 14] fp32 -> xb [N x 16] bf16 (rows padded to 32B). Also inits bcursor.
__global__ void cvt_x_bf16(const float* __restrict__ x, unsigned short* __restrict__ xb,
                           int* __restrict__ bcursor, int N, int NBH) {
    int idx = blockIdx.x * blockDim.x + threadIdx.x;
    if (idx < NBH) bcursor[idx] = idx * CAPH;
    if (idx >= N * 16) return;
    int n = idx >> 4, f = idx & 15;
    float v = (f < 14) ? x[n * 14 + f] : 0.f;
    xb[idx] = f2bf(v);
}

// Phase A: per-block counting sort into LDS over 782 half-buckets (dst>>7),
// coalesced per-run copy-out into the slack regions. dst/src loaded ONCE as
// int4 into registers. In-place scan (no tmp) keeps LDS at 2 blocks/CU.
__global__ __launch_bounds__(1024) void partitionA(
        const int* __restrict__ src, const int* __restrict__ dst,
        int* __restrict__ bcursor, unsigned* __restrict__ part, int E, int NBH) {
    __shared__ unsigned pk[CHA];                       // 64 KB staging
    __shared__ int h[MAXBH], lofs[MAXBH], cur[MAXBH], delta[MAXBH];  // 12.5 KB
    int t = threadIdx.x;
    int base = blockIdx.x * CHA;
    int end = base + CHA; if (end > E) end = E;
    int cnt = end - base;

    int ed[16], es[16];
    for (int i = t; i < NBH; i += 1024) h[i] = 0;
    __syncthreads();
    #pragma unroll
    for (int i = 0; i < 4; ++i) {
        int j = i * 4096 + t * 4;
        if (j + 4 <= cnt) {
            int4 d4 = *(const int4*)(dst + base + j);
            int4 s4 = *(const int4*)(src + base + j);
            ed[i*4+0] = d4.x; ed[i*4+1] = d4.y; ed[i*4+2] = d4.z; ed[i*4+3] = d4.w;
            es[i*4+0] = s4.x; es[i*4+1] = s4.y; es[i*4+2] = s4.z; es[i*4+3] = s4.w;
            atomicAdd(&h[d4.x >> 7], 1);
            atomicAdd(&h[d4.y >> 7], 1);
            atomicAdd(&h[d4.z >> 7], 1);
            atomicAdd(&h[d4.w >> 7], 1);
        } else {
            #pragma unroll
            for (int k = 0; k < 4; ++k) {
                if (j + k < cnt) {
                    ed[i*4+k] = dst[base + j + k];
                    es[i*4+k] = src[base + j + k];
                    atomicAdd(&h[ed[i*4+k] >> 7], 1);
                } else ed[i*4+k] = -1;
            }
        }
    }
    __syncthreads();
    int v = (t < NBH) ? h[t] : 0;
    // in-place Hillis-Steele inclusive scan over h[0..NBH)
    for (int off = 1; off < MAXBH; off <<= 1) {
        int a = 0;
        if (t < NBH && t >= off) a = h[t - off];
        __syncthreads();
        if (t < NBH) h[t] += a;
        __syncthreads();
    }
    if (t < NBH) {
        int excl = h[t] - v;
        lofs[t] = excl;
        cur[t] = excl;
        int g = v ? atomicAdd(&bcursor[t], v) : 0;   // reserve run in slack region
        delta[t] = g - excl;
    }
    __syncthreads();
    #pragma unroll
    for (int i = 0; i < 16; ++i) {
        int d = ed[i];
        if (d >= 0) {
            int b = d >> 7;
            int r = atomicAdd(&cur[b], 1);
            pk[r] = ((unsigned)(d & 127) << 24) | (unsigned)es[i];
        }
    }
    __syncthreads();
    // copy-out: cur[b] now equals the end of bucket b's run
    int wid = t >> 6, lane = t & 63;
    for (int b = wid; b < NBH; b += 16) {
        int s = lofs[b];
        int e2 = cur[b];
        int dlt = delta[b];
        int lim = (b + 1) * CAPH;                    // overflow guard (never hit)
        for (int k = s + lane; k < e2; k += 64) {
            int gidx = dlt + k;
            if (gidx < lim) part[gidx] = pk[k];
        }
    }
}

// Phase B fused, half-bucket: block hb handles 128 dst nodes, reading ONLY its
// own part region. 256-key counting sort (key = dstLocal7*2 + (src>=HALF)) in
// LDS; sorted_src written linearly; then fused LAYER-1 GATHER (8 thr/node =
// 4 edge-streams x 2 row-halves) + DENSE1 (+norm+relu).
__global__ __launch_bounds__(1024) void partitionB_fused(
        const unsigned* __restrict__ part, const int* __restrict__ bcursor,
        const uint4* __restrict__ xb4, const float* __restrict__ x,
        const float* __restrict__ W1l, const float* __restrict__ b1,
        const float* __restrict__ W1r,
        int* __restrict__ deg, int* __restrict__ offs, int* __restrict__ nlo,
        int* __restrict__ sorted_src, float* __restrict__ hbuf,
        unsigned short* __restrict__ hb, int N, int HALF) {
    __shared__ int pk2[CAPH];                          // 38 KB staging
    __shared__ int hh[256], tmp[256], keyofs[256];
    __shared__ int lstart[128], ldeg[128];
    __shared__ float sagg[128 * 17];                   // agg1 sums, stride 17
    __shared__ float sx[128 * 14];                     // x rows
    __shared__ float swl[448], swr[448], sb1[32];
    __shared__ int sTot;
    int hbid = blockIdx.x;
    int t = threadIdx.x;
    int start = hbid * CAPH;
    int end = bcursor[hbid];
    if (end > start + CAPH) end = start + CAPH;
    int cnt = end - start;
    unsigned ce[10];
    if (t < 256) hh[t] = 0;
    if (t >= 512 && t < 960) { swl[t - 512] = W1l[t - 512]; swr[t - 512] = W1r[t - 512]; }
    else if (t >= 960 && t < 992) sb1[t - 960] = b1[t - 960];
    __syncthreads();
    #pragma unroll
    for (int i = 0; i < 10; ++i) {
        int idx = start + t + i * 1024;
        unsigned p = 0xFFFFFFFFu;
        if (idx < end) {
            p = part[idx];
            int key = (int)(p >> 24) * 2 + (((int)(p & 0xFFFFFFu) < HALF) ? 0 : 1);
            atomicAdd(&hh[key], 1);
        }
        ce[i] = p;
    }
    {   // stage x rows for this half-bucket
        int nbase = hbid * 128;
        int nnod = N - nbase; if (nnod > 128) nnod = 128; if (nnod < 0) nnod = 0;
        const float* gx = x + (size_t)nbase * 14;
        for (int i = t; i < nnod * 14; i += 1024) sx[i] = gx[i];
    }
    __syncthreads();
    int v = (t < 256) ? hh[t] : 0;
    if (t < 256) tmp[t] = v;
    __syncthreads();
    for (int off = 1; off < 256; off <<= 1) {
        int a2 = (t < 256 && t >= off) ? tmp[t - off] : 0;
        __syncthreads();
        if (t < 256) tmp[t] += a2;
        __syncthreads();
    }
    if (t < 256) keyofs[t] = tmp[t] - v;               // exclusive per key
    if (t == 255) sTot = tmp[255];
    __syncthreads();
    if (t < 128) {
        int lo = hh[2 * t];
        int d = lo + hh[2 * t + 1];
        int excl = keyofs[2 * t];
        lstart[t] = excl;
        ldeg[t] = d;
        int node = hbid * 128 + t;
        if (node < N) {
            deg[node] = d;
            offs[node] = start + excl;
            nlo[node] = lo;
        }
    }
    __syncthreads();
    #pragma unroll
    for (int i = 0; i < 10; ++i) {
        unsigned p = ce[i];
        if (p != 0xFFFFFFFFu) {
            int s = (int)(p & 0xFFFFFFu);
            int key = (int)(p >> 24) * 2 + ((s < HALF) ? 0 : 1);
            int r = atomicAdd(&keyofs[key], 1);
            if (r < CAPH) pk2[r] = s;
        }
    }
    __syncthreads();
    int tot = sTot; if (tot > CAPH) tot = CAPH;
    for (int i = t; i < tot; i += 1024)
        sorted_src[start + i] = pk2[i];

    // ---- fused layer-1 gather: 8 threads/node = 4 edge-streams x 2 row-halves
    int node = t >> 3, sub = t & 7, ep = sub >> 1, half = sub & 1;
    int js = lstart[node], d = ldeg[node];
    int je = js + d;
    float a[8] = {0,0,0,0,0,0,0,0};
    int j = js + ep;
    for (; j + 4 < je; j += 8) {                      // 2 edges/iter per stream
        int s0 = pk2[j], s1 = pk2[j + 4];
        uint4 u0 = xb4[s0 * 2 + half], u1 = xb4[s1 * 2 + half];
        a[0] += BF_LO(u0.x) + BF_LO(u1.x);
        a[1] += BF_HI(u0.x) + BF_HI(u1.x);
        a[2] += BF_LO(u0.y) + BF_LO(u1.y);
        a[3] += BF_HI(u0.y) + BF_HI(u1.y);
        a[4] += BF_LO(u0.z) + BF_LO(u1.z);
        a[5] += BF_HI(u0.z) + BF_HI(u1.z);
        a[6] += BF_LO(u0.w) + BF_LO(u1.w);
        a[7] += BF_HI(u0.w) + BF_HI(u1.w);
    }
    for (; j < je; j += 4) {
        uint4 u0 = xb4[pk2[j] * 2 + half];
        a[0] += BF_LO(u0.x); a[1] += BF_HI(u0.x);
        a[2] += BF_LO(u0.y); a[3] += BF_HI(u0.y);
        a[4] += BF_LO(u0.z); a[5] += BF_HI(u0.z);
        a[6] += BF_LO(u0.w); a[7] += BF_HI(u0.w);
    }
    #pragma unroll
    for (int i = 0; i < 8; ++i) {
        a[i] += __shfl_xor(a[i], 2);                  // merge stream pairs
        a[i] += __shfl_xor(a[i], 4);                  // merge all 4 streams
    }
    if (ep == 0) {                                     // sub in {0,1}: both halves
        #pragma unroll
        for (int i = 0; i < 8; ++i) sagg[node * 17 + half * 8 + i] = a[i];
    }
    __syncthreads();

    // ---- fused dense1: 8 threads/node, each computes 4 of 32 outputs
    float inv = 1.0f / ((d > 0) ? (float)d : 1.0f);
    float acc[4];
    #pragma unroll
    for (int i = 0; i < 4; ++i) acc[i] = sb1[sub * 4 + i];
    #pragma unroll
    for (int k = 0; k < 14; ++k) {
        float ag = sagg[node * 17 + k] * inv;
        float xv = sx[node * 14 + k];
        float4 wl = *(const float4*)&swl[k * 32 + sub * 4];
        float4 wr = *(const float4*)&swr[k * 32 + sub * 4];
        acc[0] += ag * wl.x + xv * wr.x;
        acc[1] += ag * wl.y + xv * wr.y;
        acc[2] += ag * wl.z + xv * wr.z;
        acc[3] += ag * wl.w + xv * wr.w;
    }
    float ss = 0.f;
    #pragma unroll
    for (int i = 0; i < 4; ++i) ss += acc[i] * acc[i];
    ss += __shfl_xor(ss, 1); ss += __shfl_xor(ss, 2); ss += __shfl_xor(ss, 4);
    float invn = 1.f / fmaxf(sqrtf(ss), 1e-12f);
    int gnode = hbid * 128 + node;
    if (gnode < N) {
        float hv[4];
        #pragma unroll
        for (int i = 0; i < 4; ++i) hv[i] = fmaxf(acc[i] * invn, 0.f);
        *(float4*)(hbuf + (size_t)gnode * 32 + sub * 4) =
            make_float4(hv[0], hv[1], hv[2], hv[3]);
        uint2 pb;
        pb.x = (unsigned)f2bf(hv[0]) | ((unsigned)f2bf(hv[1]) << 16);
        pb.y = (unsigned)f2bf(hv[2]) | ((unsigned)f2bf(hv[3]) << 16);
        *(uint2*)(hb + (size_t)gnode * 32 + sub * 4) = pb;
    }
}

// Layer-2 gather pass 0 (src < HALF; table half 3.2MB bf16, L2-resident).
__global__ void gather32_p0(const uint4* __restrict__ hb, const int* __restrict__ sorted_src,
                            const int* __restrict__ offs, const int* __restrict__ nlo,
                            float4* __restrict__ agg2, int N) {
    int idx = blockIdx.x * blockDim.x + threadIdx.x;
    int n = idx >> 2;
    if (n >= N) return;
    int q = idx & 3;
    int start = offs[n];
    int jend = nlo[n];
    float a0=0,a1=0,a2=0,a3=0,a4=0,a5=0,a6=0,a7=0;
    int j = 0;
    for (; j + 4 <= jend; j += 4) {
        int s0 = sorted_src[start + j + 0];
        int s1 = sorted_src[start + j + 1];
        int s2 = sorted_src[start + j + 2];
        int s3 = sorted_src[start + j + 3];
        uint4 u0 = hb[s0 * 4 + q];
        uint4 u1 = hb[s1 * 4 + q];
        uint4 u2 = hb[s2 * 4 + q];
        uint4 u3 = hb[s3 * 4 + q];
        a0 += BF_LO(u0.x) + BF_LO(u1.x) + BF_LO(u2.x) + BF_LO(u3.x);
        a1 += BF_HI(u0.x) + BF_HI(u1.x) + BF_HI(u2.x) + BF_HI(u3.x);
        a2 += BF_LO(u0.y) + BF_LO(u1.y) + BF_LO(u2.y) + BF_LO(u3.y);
        a3 += BF_HI(u0.y) + BF_HI(u1.y) + BF_HI(u2.y) + BF_HI(u3.y);
        a4 += BF_LO(u0.z) + BF_LO(u1.z) + BF_LO(u2.z) + BF_LO(u3.z);
        a5 += BF_HI(u0.z) + BF_HI(u1.z) + BF_HI(u2.z) + BF_HI(u3.z);
        a6 += BF_LO(u0.w) + BF_LO(u1.w) + BF_LO(u2.w) + BF_LO(u3.w);
        a7 += BF_HI(u0.w) + BF_HI(u1.w) + BF_HI(u2.w) + BF_HI(u3.w);
    }
    for (; j < jend; ++j) {
        uint4 u0 = hb[sorted_src[start + j] * 4 + q];
        a0 += BF_LO(u0.x); a1 += BF_HI(u0.x);
        a2 += BF_LO(u0.y); a3 += BF_HI(u0.y);
        a4 += BF_LO(u0.z); a5 += BF_HI(u0.z);
        a6 += BF_LO(u0.w); a7 += BF_HI(u0.w);
    }
    agg2[n * 8 + q * 2 + 0] = make_float4(a0, a1, a2, a3);
    agg2[n * 8 + q * 2 + 1] = make_float4(a4, a5, a6, a7);
}

// Layer-2 gather pass 1 (src >= HALF): adds to pass-0 sums, applies 1/deg.
__global__ void gather32_p1(const uint4* __restrict__ hb, const int* __restrict__ sorted_src,
                            const int* __restrict__ offs, const int* __restrict__ deg,
                            const int* __restrict__ nlo, float4* __restrict__ agg2, int N) {
    int idx = blockIdx.x * blockDim.x + threadIdx.x;
    int n = idx >> 2;
    if (n >= N) return;
    int q = idx & 3;
    int start = offs[n];
    int d = deg[n];
    int j = nlo[n];
    float a0=0,a1=0,a2=0,a3=0,a4=0,a5=0,a6=0,a7=0;
    for (; j + 4 <= d; j += 4) {
        int s0 = sorted_src[start + j + 0];
        int s1 = sorted_src[start + j + 1];
        int s2 = sorted_src[start + j + 2];
        int s3 = sorted_src[start + j + 3];
        uint4 u0 = hb[s0 * 4 + q];
        uint4 u1 = hb[s1 * 4 + q];
        uint4 u2 = hb[s2 * 4 + q];
        uint4 u3 = hb[s3 * 4 + q];
        a0 += BF_LO(u0.x) + BF_LO(u1.x) + BF_LO(u2.x) + BF_LO(u3.x);
        a1 += BF_HI(u0.x) + BF_HI(u1.x) + BF_HI(u2.x) + BF_HI(u3.x);
        a2 += BF_LO(u0.y) + BF_LO(u1.y) + BF_LO(u2.y) + BF_LO(u3.y);
        a3 += BF_HI(u0.y) + BF_HI(u1.y) + BF_HI(u2.y) + BF_HI(u3.y);
        a4 += BF_LO(u0.z) + BF_LO(u1.z) + BF_LO(u2.z) + BF_LO(u3.z);
        a5 += BF_HI(u0.z) + BF_HI(u1.z) + BF_HI(u2.z) + BF_HI(u3.z);
        a6 += BF_LO(u0.w) + BF_LO(u1.w) + BF_LO(u2.w) + BF_LO(u3.w);
        a7 += BF_HI(u0.w) + BF_HI(u1.w) + BF_HI(u2.w) + BF_HI(u3.w);
    }
    for (; j < d; ++j) {
        uint4 u0 = hb[sorted_src[start + j] * 4 + q];
        a0 += BF_LO(u0.x); a1 += BF_HI(u0.x);
        a2 += BF_LO(u0.y); a3 += BF_HI(u0.y);
        a4 += BF_LO(u0.z); a5 += BF_HI(u0.z);
        a6 += BF_LO(u0.w); a7 += BF_HI(u0.w);
    }
    float inv = 1.0f / ((d > 0) ? (float)d : 1.0f);
    float4 p0 = agg2[n * 8 + q * 2 + 0];
    float4 p1 = agg2[n * 8 + q * 2 + 1];
    agg2[n * 8 + q * 2 + 0] = make_float4((p0.x + a0) * inv, (p0.y + a1) * inv,
                                          (p0.z + a2) * inv, (p0.w + a3) * inv);
    agg2[n * 8 + q * 2 + 1] = make_float4((p1.x + a4) * inv, (p1.y + a5) * inv,
                                          (p1.z + a6) * inv, (p1.w + a7) * inv);
}

// Layer 2 + final linear, tiled (conflict-free padded strides, VGPR ~36).
__global__ __launch_bounds__(256) void dense2(
        const float* __restrict__ h, const float* __restrict__ agg2,
        const float* __restrict__ W2l, const float* __restrict__ b2,
        const float* __restrict__ W2r, const float* __restrict__ Wlin,
        const float* __restrict__ blin, float* __restrict__ out, int N) {
    __shared__ float sa[NPB * 33];
    __shared__ float sh2[NPB * 33];
    __shared__ float swl[32 * 32], swr[32 * 32], swo[64], sb[32], sbo[2];
    int t = threadIdx.x;
    int nb = blockIdx.x * NPB;
    int nn = N - nb; if (nn > NPB) nn = NPB;
    const float4* ga = (const float4*)(agg2 + (size_t)nb * 32);
    const float4* gh = (const float4*)(h + (size_t)nb * 32);
    for (int i = t; i < nn * 8; i += 256) {
        float4 v = ga[i];
        float* d = &sa[(i >> 3) * 33 + (i & 7) * 4];
        d[0] = v.x; d[1] = v.y; d[2] = v.z; d[3] = v.w;
        float4 w = gh[i];
        float* e = &sh2[(i >> 3) * 33 + (i & 7) * 4];
        e[0] = w.x; e[1] = w.y; e[2] = w.z; e[3] = w.w;
    }
    for (int i = t; i < 1024; i += 256) { swl[i] = W2l[i]; swr[i] = W2r[i]; }
    if (t < 64) swo[t] = Wlin[t];
    if (t < 32) sb[t] = b2[t];
    if (t < 2) sbo[t] = blin[t];
    __syncthreads();
    int q2 = t & 3;
    int p = t >> 2;
    int l0 = p * 2, l1 = l0 + 1;
    float acc0[8], acc1[8];
    #pragma unroll
    for (int j = 0; j < 8; ++j) { acc0[j] = sb[q2 * 8 + j]; acc1[j] = acc0[j]; }
    for (int k = 0; k < 32; ++k) {
        float a0 = sa[l0 * 33 + k],  a1 = sa[l1 * 33 + k];
        float h0 = sh2[l0 * 33 + k], h1 = sh2[l1 * 33 + k];
        const float4* wl4 = (const float4*)&swl[k * 32 + q2 * 8];
        const float4* wr4 = (const float4*)&swr[k * 32 + q2 * 8];
        float4 wla = wl4[0], wlb = wl4[1], wra = wr4[0], wrb = wr4[1];
        acc0[0] += a0 * wla.x + h0 * wra.x;  acc1[0] += a1 * wla.x + h1 * wra.x;
        acc0[1] += a0 * wla.y + h0 * wra.y;  acc1[1] += a1 * wla.y + h1 * wra.y;
        acc0[2] += a0 * wla.z + h0 * wra.z;  acc1[2] += a1 * wla.z + h1 * wra.z;
        acc0[3] += a0 * wla.w + h0 * wra.w;  acc1[3] += a1 * wla.w + h1 * wra.w;
        acc0[4] += a0 * wlb.x + h0 * wrb.x;  acc1[4] += a1 * wlb.x + h1 * wrb.x;
        acc0[5] += a0 * wlb.y + h0 * wrb.y;  acc1[5] += a1 * wlb.y + h1 * wrb.y;
        acc0[6] += a0 * wlb.z + h0 * wrb.z;  acc1[6] += a1 * wlb.z + h1 * wrb.z;
        acc0[7] += a0 * wlb.w + h0 * wrb.w;  acc1[7] += a1 * wlb.w + h1 * wrb.w;
    }
    float ss0 = 0.f, ss1 = 0.f;
    #pragma unroll
    for (int j = 0; j < 8; ++j) { ss0 += acc0[j] * acc0[j]; ss1 += acc1[j] * acc1[j]; }
    ss0 += __shfl_xor(ss0, 1); ss0 += __shfl_xor(ss0, 2);
    ss1 += __shfl_xor(ss1, 1); ss1 += __shfl_xor(ss1, 2);
    float inv0 = 1.f / fmaxf(sqrtf(ss0), 1e-12f);
    float inv1 = 1.f / fmaxf(sqrtf(ss1), 1e-12f);
    float o00 = 0.f, o01 = 0.f, o10 = 0.f, o11 = 0.f;
    #pragma unroll
    for (int j = 0; j < 8; ++j) {
        float hv0 = fmaxf(acc0[j] * inv0, 0.f);
        float hv1 = fmaxf(acc1[j] * inv1, 0.f);
        int kk = q2 * 8 + j;
        o00 += hv0 * swo[kk * 2 + 0];
        o01 += hv0 * swo[kk * 2 + 1];
        o10 += hv1 * swo[kk * 2 + 0];
        o11 += hv1 * swo[kk * 2 + 1];
    }
    o00 += __shfl_xor(o00, 1); o00 += __shfl_xor(o00, 2);
    o01 += __shfl_xor(o01, 1); o01 += __shfl_xor(o01, 2);
    o10 += __shfl_xor(o10, 1); o10 += __shfl_xor(o10, 2);
    o11 += __shfl_xor(o11, 1); o11 += __shfl_xor(o11, 2);
    if (q2 == 0) {
        int n0 = nb + l0, n1 = nb + l1;
        if (n0 < N) { out[n0 * 2 + 0] = o00 + sbo[0]; out[n0 * 2 + 1] = o01 + sbo[1]; }
        if (n1 < N) { out[n1 * 2 + 0] = o10 + sbo[0]; out[n1 * 2 + 1] = o11 + sbo[1]; }
    }
}

extern "C" void kernel_launch(void* const* d_in, const int* in_sizes, int n_in,
                              void* d_out, int out_size, void* d_ws, size_t ws_size,
                              hipStream_t stream) {
    const float* x    = (const float*)d_in[0];
    const int*   ei   = (const int*)d_in[1];
    const float* W1l  = (const float*)d_in[2];
    const float* b1   = (const float*)d_in[3];
    const float* W1r  = (const float*)d_in[4];
    const float* W2l  = (const float*)d_in[5];
    const float* b2   = (const float*)d_in[6];
    const float* W2r  = (const float*)d_in[7];
    const float* Wlin = (const float*)d_in[8];
    const float* blin = (const float*)d_in[9];
    float* out = (float*)d_out;

    const int N = in_sizes[0] / 14;
    const int E = in_sizes[1] / 2;
    const int* src = ei;
    const int* dst = ei + E;
    const int NBH = (N + 127) / 128;  // 782 half-buckets
    const int HALF = N / 2;

    char* ws = (char*)d_ws;
    size_t off = 0;
    auto alloc = [&](size_t bytes) -> void* {
        void* p = ws + off;
        off = (off + bytes + 255) & ~(size_t)255;
        return p;
    };
    int*            bcursor    = (int*)alloc((size_t)NBH * 4);
    unsigned*       part       = (unsigned*)alloc((size_t)NBH * CAPH * 4);  // dead after partitionB
    int*            sorted_src = (int*)alloc((size_t)NBH * CAPH * 4);
    int*            deg        = (int*)alloc((size_t)N * 4);
    int*            offs       = (int*)alloc((size_t)N * 4);
    int*            nlo        = (int*)alloc((size_t)N * 4);
    unsigned short* xb         = (unsigned short*)alloc((size_t)N * 16 * 2);
    float*          hbuf       = (float*)alloc((size_t)N * 32 * 4);
    unsigned short* hb         = (unsigned short*)alloc((size_t)N * 32 * 2);
    float*          agg2       = (float*)part;                              // alias dead part buffer
    (void)ws_size; (void)n_in; (void)out_size;

    cvt_x_bf16<<<(N * 16 + 255) / 256, 256, 0, stream>>>(x, xb, bcursor, N, NBH);
    partitionA<<<(E + CHA - 1) / CHA, 1024, 0, stream>>>(src, dst, bcursor, part, E, NBH);
    partitionB_fused<<<NBH, 1024, 0, stream>>>(
        part, bcursor, (const uint4*)xb, x, W1l, b1, W1r,
        deg, offs, nlo, sorted_src, hbuf, hb, N, HALF);
    gather32_p0<<<(N * 4 + 255) / 256, 256, 0, stream>>>(
        (const uint4*)hb, sorted_src, offs, nlo, (float4*)agg2, N);
    gather32_p1<<<(N * 4 + 255) / 256, 256, 0, stream>>>(
        (const uint4*)hb, sorted_src, offs, deg, nlo, (float4*)agg2, N);
    dense2<<<(N + NPB - 1) / NPB, 256, 0, stream>>>(
        hbuf, agg2, W2l, b2, W2r, Wlin, blin, out, N);
}

// Round 14
// 273.249 us; speedup vs baseline: 1.0182x; 1.0106x over previous
//
#include <hip/hip_runtime.h>
#include <hip/hip_bf16.h>

// GraphSAGE (2x SAGEConv mean + normalize + relu, final linear) on MI355X.
// R14: rank-from-histogram. Both partition kernels paid LDS atomics twice per
// edge (histogram + scatter cursor). The histogram atomicAdd already returns
// the edge's local rank within its key; storing it in registers makes the
// scatter position excl[key]+rank — plain read+add, no serialized atomic
// chains on hot keys. partitionA's cur[] deleted; copy-out end = inclusive
// scan value.

#define CHA 16384   // edges per phase-A block
#define MAXBH 800   // max half-buckets (NBH = ceil(N/128) = 782)
#define CAPH 9728   // slots per 128-node half-bucket region (mean ~8.2K, ~17 sigma)
#define NPB 128     // nodes per dense block

static __device__ __forceinline__ unsigned short f2bf(float f) {
    unsigned u = __float_as_uint(f);
    unsigned r = (u + 0x7FFFu + ((u >> 16) & 1u)) >> 16;   // RTN-even
    return (unsigned short)r;
}
#define BF_LO(u) __uint_as_float((u) << 16)
#define BF_HI(u) __uint_as_float((u) & 0xFFFF0000u)

// x [N x 14] fp32 -> xb [N x 16] bf16 (rows padded to 32B). Also inits bcursor.
__global__ void cvt_x_bf16(const float* __restrict__ x, unsigned short* __restrict__ xb,
                           int* __restrict__ bcursor, int N, int NBH) {
    int idx = blockIdx.x * blockDim.x + threadIdx.x;
    if (idx < NBH) bcursor[idx] = idx * CAPH;
    if (idx >= N * 16) return;
    int n = idx >> 4, f = idx & 15;
    float v = (f < 14) ? x[n * 14 + f] : 0.f;
    xb[idx] = f2bf(v);
}

// Phase A: per-block counting sort into LDS over 782 half-buckets (dst>>7),
// coalesced per-run copy-out. dst/src loaded ONCE as int4 into registers;
// local rank captured from the histogram atomic -> scatter is read+add.
__global__ __launch_bounds__(1024) void partitionA(
        const int* __restrict__ src, const int* __restrict__ dst,
        int* __restrict__ bcursor, unsigned* __restrict__ part, int E, int NBH) {
    __shared__ unsigned pk[CHA];                       // 64 KB staging
    __shared__ int h[MAXBH], lofs[MAXBH], delta[MAXBH];  // 9.4 KB
    int t = threadIdx.x;
    int base = blockIdx.x * CHA;
    int end = base + CHA; if (end > E) end = E;
    int cnt = end - base;

    int ed[16], es[16], er[16];
    for (int i = t; i < NBH; i += 1024) h[i] = 0;
    __syncthreads();
    #pragma unroll
    for (int i = 0; i < 4; ++i) {
        int j = i * 4096 + t * 4;
        if (j + 4 <= cnt) {
            int4 d4 = *(const int4*)(dst + base + j);
            int4 s4 = *(const int4*)(src + base + j);
            ed[i*4+0] = d4.x; ed[i*4+1] = d4.y; ed[i*4+2] = d4.z; ed[i*4+3] = d4.w;
            es[i*4+0] = s4.x; es[i*4+1] = s4.y; es[i*4+2] = s4.z; es[i*4+3] = s4.w;
            er[i*4+0] = atomicAdd(&h[d4.x >> 7], 1);
            er[i*4+1] = atomicAdd(&h[d4.y >> 7], 1);
            er[i*4+2] = atomicAdd(&h[d4.z >> 7], 1);
            er[i*4+3] = atomicAdd(&h[d4.w >> 7], 1);
        } else {
            #pragma unroll
            for (int k = 0; k < 4; ++k) {
                if (j + k < cnt) {
                    ed[i*4+k] = dst[base + j + k];
                    es[i*4+k] = src[base + j + k];
                    er[i*4+k] = atomicAdd(&h[ed[i*4+k] >> 7], 1);
                } else ed[i*4+k] = -1;
            }
        }
    }
    __syncthreads();
    int v = (t < NBH) ? h[t] : 0;
    // in-place Hillis-Steele inclusive scan over h[0..NBH)
    for (int off = 1; off < MAXBH; off <<= 1) {
        int a = 0;
        if (t < NBH && t >= off) a = h[t - off];
        __syncthreads();
        if (t < NBH) h[t] += a;
        __syncthreads();
    }
    if (t < NBH) {
        int excl = h[t] - v;
        lofs[t] = excl;
        int g = v ? atomicAdd(&bcursor[t], v) : 0;   // reserve run in slack region
        delta[t] = g - excl;
    }
    __syncthreads();
    #pragma unroll
    for (int i = 0; i < 16; ++i) {
        int d = ed[i];
        if (d >= 0) {
            int b = d >> 7;
            pk[lofs[b] + er[i]] = ((unsigned)(d & 127) << 24) | (unsigned)es[i];
        }
    }
    __syncthreads();
    // copy-out: h[b] (inclusive scan) is the end of bucket b's run
    int wid = t >> 6, lane = t & 63;
    for (int b = wid; b < NBH; b += 16) {
        int s = lofs[b];
        int e2 = h[b];
        int dlt = delta[b];
        int lim = (b + 1) * CAPH;                    // overflow guard (never hit)
        for (int k = s + lane; k < e2; k += 64) {
            int gidx = dlt + k;
            if (gidx < lim) part[gidx] = pk[k];
        }
    }
}

// Phase B fused, half-bucket: block hb handles 128 dst nodes, reading ONLY its
// own part region. 256-key counting sort (key = dstLocal7*2 + (src>=HALF)),
// ranks captured from the histogram atomics; sorted_src written linearly; then
// fused LAYER-1 GATHER (8 thr/node = 4 edge-streams x 2 row-halves) + DENSE1.
__global__ __launch_bounds__(1024) void partitionB_fused(
        const unsigned* __restrict__ part, const int* __restrict__ bcursor,
        const uint4* __restrict__ xb4, const float* __restrict__ x,
        const float* __restrict__ W1l, const float* __restrict__ b1,
        const float* __restrict__ W1r,
        int* __restrict__ deg, int* __restrict__ offs, int* __restrict__ nlo,
        int* __restrict__ sorted_src, float* __restrict__ hbuf,
        unsigned short* __restrict__ hb, int N, int HALF) {
    __shared__ int pk2[CAPH];                          // 38 KB staging
    __shared__ int hh[256], keyofs[256];
    __shared__ int lstart[128], ldeg[128];
    __shared__ float sagg[128 * 17];                   // agg1 sums, stride 17
    __shared__ float sx[128 * 14];                     // x rows
    __shared__ float swl[448], swr[448], sb1[32];
    __shared__ int sTot;
    int hbid = blockIdx.x;
    int t = threadIdx.x;
    int start = hbid * CAPH;
    int end = bcursor[hbid];
    if (end > start + CAPH) end = start + CAPH;
    int cnt = end - start;
    unsigned ce[10];
    int rk[10];
    if (t < 256) hh[t] = 0;
    if (t >= 512 && t < 960) { swl[t - 512] = W1l[t - 512]; swr[t - 512] = W1r[t - 512]; }
    else if (t >= 960 && t < 992) sb1[t - 960] = b1[t - 960];
    __syncthreads();
    #pragma unroll
    for (int i = 0; i < 10; ++i) {
        int idx = start + t + i * 1024;
        unsigned p = 0xFFFFFFFFu;
        int r = 0;
        if (idx < end) {
            p = part[idx];
            int key = (int)(p >> 24) * 2 + (((int)(p & 0xFFFFFFu) < HALF) ? 0 : 1);
            r = atomicAdd(&hh[key], 1);
        }
        ce[i] = p;
        rk[i] = r;
    }
    {   // stage x rows for this half-bucket
        int nbase = hbid * 128;
        int nnod = N - nbase; if (nnod > 128) nnod = 128; if (nnod < 0) nnod = 0;
        const float* gx = x + (size_t)nbase * 14;
        for (int i = t; i < nnod * 14; i += 1024) sx[i] = gx[i];
    }
    __syncthreads();
    int v = (t < 256) ? hh[t] : 0;
    if (t < 256) keyofs[t] = v;
    __syncthreads();
    // in-place inclusive scan over keyofs
    for (int off = 1; off < 256; off <<= 1) {
        int a2 = (t < 256 && t >= off) ? keyofs[t - off] : 0;
        __syncthreads();
        if (t < 256) keyofs[t] += a2;
        __syncthreads();
    }
    if (t < 256) keyofs[t] -= v;                       // exclusive per key
    if (t == 255) sTot = keyofs[255] + v;
    __syncthreads();
    if (t < 128) {
        int lo = hh[2 * t];
        int d = lo + hh[2 * t + 1];
        int excl = keyofs[2 * t];
        lstart[t] = excl;
        ldeg[t] = d;
        int node = hbid * 128 + t;
        if (node < N) {
            deg[node] = d;
            offs[node] = start + excl;
            nlo[node] = lo;
        }
    }
    __syncthreads();
    #pragma unroll
    for (int i = 0; i < 10; ++i) {
        unsigned p = ce[i];
        if (p != 0xFFFFFFFFu) {
            int s = (int)(p & 0xFFFFFFu);
            int key = (int)(p >> 24) * 2 + ((s < HALF) ? 0 : 1);
            int pos = keyofs[key] + rk[i];
            if (pos < CAPH) pk2[pos] = s;
        }
    }
    __syncthreads();
    int tot = sTot; if (tot > CAPH) tot = CAPH;
    for (int i = t; i < tot; i += 1024)
        sorted_src[start + i] = pk2[i];

    // ---- fused layer-1 gather: 8 threads/node = 4 edge-streams x 2 row-halves
    int node = t >> 3, sub = t & 7, ep = sub >> 1, half = sub & 1;
    int js = lstart[node], d = ldeg[node];
    int je = js + d;
    float a[8] = {0,0,0,0,0,0,0,0};
    int j = js + ep;
    for (; j + 4 < je; j += 8) {                      // 2 edges/iter per stream
        int s0 = pk2[j], s1 = pk2[j + 4];
        uint4 u0 = xb4[s0 * 2 + half], u1 = xb4[s1 * 2 + half];
        a[0] += BF_LO(u0.x) + BF_LO(u1.x);
        a[1] += BF_HI(u0.x) + BF_HI(u1.x);
        a[2] += BF_LO(u0.y) + BF_LO(u1.y);
        a[3] += BF_HI(u0.y) + BF_HI(u1.y);
        a[4] += BF_LO(u0.z) + BF_LO(u1.z);
        a[5] += BF_HI(u0.z) + BF_HI(u1.z);
        a[6] += BF_LO(u0.w) + BF_LO(u1.w);
        a[7] += BF_HI(u0.w) + BF_HI(u1.w);
    }
    for (; j < je; j += 4) {
        uint4 u0 = xb4[pk2[j] * 2 + half];
        a[0] += BF_LO(u0.x); a[1] += BF_HI(u0.x);
        a[2] += BF_LO(u0.y); a[3] += BF_HI(u0.y);
        a[4] += BF_LO(u0.z); a[5] += BF_HI(u0.z);
        a[6] += BF_LO(u0.w); a[7] += BF_HI(u0.w);
    }
    #pragma unroll
    for (int i = 0; i < 8; ++i) {
        a[i] += __shfl_xor(a[i], 2);                  // merge stream pairs
        a[i] += __shfl_xor(a[i], 4);                  // merge all 4 streams
    }
    if (ep == 0) {                                     // sub in {0,1}: both halves
        #pragma unroll
        for (int i = 0; i < 8; ++i) sagg[node * 17 + half * 8 + i] = a[i];
    }
    __syncthreads();

    // ---- fused dense1: 8 threads/node, each computes 4 of 32 outputs
    float inv = 1.0f / ((d > 0) ? (float)d : 1.0f);
    float acc[4];
    #pragma unroll
    for (int i = 0; i < 4; ++i) acc[i] = sb1[sub * 4 + i];
    #pragma unroll
    for (int k = 0; k < 14; ++k) {
        float ag = sagg[node * 17 + k] * inv;
        float xv = sx[node * 14 + k];
        float4 wl = *(const float4*)&swl[k * 32 + sub * 4];
        float4 wr = *(const float4*)&swr[k * 32 + sub * 4];
        acc[0] += ag * wl.x + xv * wr.x;
        acc[1] += ag * wl.y + xv * wr.y;
        acc[2] += ag * wl.z + xv * wr.z;
        acc[3] += ag * wl.w + xv * wr.w;
    }
    float ss = 0.f;
    #pragma unroll
    for (int i = 0; i < 4; ++i) ss += acc[i] * acc[i];
    ss += __shfl_xor(ss, 1); ss += __shfl_xor(ss, 2); ss += __shfl_xor(ss, 4);
    float invn = 1.f / fmaxf(sqrtf(ss), 1e-12f);
    int gnode = hbid * 128 + node;
    if (gnode < N) {
        float hv[4];
        #pragma unroll
        for (int i = 0; i < 4; ++i) hv[i] = fmaxf(acc[i] * invn, 0.f);
        *(float4*)(hbuf + (size_t)gnode * 32 + sub * 4) =
            make_float4(hv[0], hv[1], hv[2], hv[3]);
        uint2 pb;
        pb.x = (unsigned)f2bf(hv[0]) | ((unsigned)f2bf(hv[1]) << 16);
        pb.y = (unsigned)f2bf(hv[2]) | ((unsigned)f2bf(hv[3]) << 16);
        *(uint2*)(hb + (size_t)gnode * 32 + sub * 4) = pb;
    }
}

// Layer-2 gather pass 0 (src < HALF; table half 3.2MB bf16, L2-resident).
__global__ void gather32_p0(const uint4* __restrict__ hb, const int* __restrict__ sorted_src,
                            const int* __restrict__ offs, const int* __restrict__ nlo,
                            float4* __restrict__ agg2, int N) {
    int idx = blockIdx.x * blockDim.x + threadIdx.x;
    int n = idx >> 2;
    if (n >= N) return;
    int q = idx & 3;
    int start = offs[n];
    int jend = nlo[n];
    float a0=0,a1=0,a2=0,a3=0,a4=0,a5=0,a6=0,a7=0;
    int j = 0;
    for (; j + 4 <= jend; j += 4) {
        int s0 = sorted_src[start + j + 0];
        int s1 = sorted_src[start + j + 1];
        int s2 = sorted_src[start + j + 2];
        int s3 = sorted_src[start + j + 3];
        uint4 u0 = hb[s0 * 4 + q];
        uint4 u1 = hb[s1 * 4 + q];
        uint4 u2 = hb[s2 * 4 + q];
        uint4 u3 = hb[s3 * 4 + q];
        a0 += BF_LO(u0.x) + BF_LO(u1.x) + BF_LO(u2.x) + BF_LO(u3.x);
        a1 += BF_HI(u0.x) + BF_HI(u1.x) + BF_HI(u2.x) + BF_HI(u3.x);
        a2 += BF_LO(u0.y) + BF_LO(u1.y) + BF_LO(u2.y) + BF_LO(u3.y);
        a3 += BF_HI(u0.y) + BF_HI(u1.y) + BF_HI(u2.y) + BF_HI(u3.y);
        a4 += BF_LO(u0.z) + BF_LO(u1.z) + BF_LO(u2.z) + BF_LO(u3.z);
        a5 += BF_HI(u0.z) + BF_HI(u1.z) + BF_HI(u2.z) + BF_HI(u3.z);
        a6 += BF_LO(u0.w) + BF_LO(u1.w) + BF_LO(u2.w) + BF_LO(u3.w);
        a7 += BF_HI(u0.w) + BF_HI(u1.w) + BF_HI(u2.w) + BF_HI(u3.w);
    }
    for (; j < jend; ++j) {
        uint4 u0 = hb[sorted_src[start + j] * 4 + q];
        a0 += BF_LO(u0.x); a1 += BF_HI(u0.x);
        a2 += BF_LO(u0.y); a3 += BF_HI(u0.y);
        a4 += BF_LO(u0.z); a5 += BF_HI(u0.z);
        a6 += BF_LO(u0.w); a7 += BF_HI(u0.w);
    }
    agg2[n * 8 + q * 2 + 0] = make_float4(a0, a1, a2, a3);
    agg2[n * 8 + q * 2 + 1] = make_float4(a4, a5, a6, a7);
}

// Layer-2 gather pass 1 (src >= HALF): adds to pass-0 sums, applies 1/deg.
__global__ void gather32_p1(const uint4* __restrict__ hb, const int* __restrict__ sorted_src,
                            const int* __restrict__ offs, const int* __restrict__ deg,
                            const int* __restrict__ nlo, float4* __restrict__ agg2, int N) {
    int idx = blockIdx.x * blockDim.x + threadIdx.x;
    int n = idx >> 2;
    if (n >= N) return;
    int q = idx & 3;
    int start = offs[n];
    int d = deg[n];
    int j = nlo[n];
    float a0=0,a1=0,a2=0,a3=0,a4=0,a5=0,a6=0,a7=0;
    for (; j + 4 <= d; j += 4) {
        int s0 = sorted_src[start + j + 0];
        int s1 = sorted_src[start + j + 1];
        int s2 = sorted_src[start + j + 2];
        int s3 = sorted_src[start + j + 3];
        uint4 u0 = hb[s0 * 4 + q];
        uint4 u1 = hb[s1 * 4 + q];
        uint4 u2 = hb[s2 * 4 + q];
        uint4 u3 = hb[s3 * 4 + q];
        a0 += BF_LO(u0.x) + BF_LO(u1.x) + BF_LO(u2.x) + BF_LO(u3.x);
        a1 += BF_HI(u0.x) + BF_HI(u1.x) + BF_HI(u2.x) + BF_HI(u3.x);
        a2 += BF_LO(u0.y) + BF_LO(u1.y) + BF_LO(u2.y) + BF_LO(u3.y);
        a3 += BF_HI(u0.y) + BF_HI(u1.y) + BF_HI(u2.y) + BF_HI(u3.y);
        a4 += BF_LO(u0.z) + BF_LO(u1.z) + BF_LO(u2.z) + BF_LO(u3.z);
        a5 += BF_HI(u0.z) + BF_HI(u1.z) + BF_HI(u2.z) + BF_HI(u3.z);
        a6 += BF_LO(u0.w) + BF_LO(u1.w) + BF_LO(u2.w) + BF_LO(u3.w);
        a7 += BF_HI(u0.w) + BF_HI(u1.w) + BF_HI(u2.w) + BF_HI(u3.w);
    }
    for (; j < d; ++j) {
        uint4 u0 = hb[sorted_src[start + j] * 4 + q];
        a0 += BF_LO(u0.x); a1 += BF_HI(u0.x);
        a2 += BF_LO(u0.y); a3 += BF_HI(u0.y);
        a4 += BF_LO(u0.z); a5 += BF_HI(u0.z);
        a6 += BF_LO(u0.w); a7 += BF_HI(u0.w);
    }
    float inv = 1.0f / ((d > 0) ? (float)d : 1.0f);
    float4 p0 = agg2[n * 8 + q * 2 + 0];
    float4 p1 = agg2[n * 8 + q * 2 + 1];
    agg2[n * 8 + q * 2 + 0] = make_float4((p0.x + a0) * inv, (p0.y + a1) * inv,
                                          (p0.z + a2) * inv, (p0.w + a3) * inv);
    agg2[n * 8 + q * 2 + 1] = make_float4((p1.x + a4) * inv, (p1.y + a5) * inv,
                                          (p1.z + a6) * inv, (p1.w + a7) * inv);
}

// Layer 2 + final linear, tiled (conflict-free padded strides, VGPR ~36).
__global__ __launch_bounds__(256) void dense2(
        const float* __restrict__ h, const float* __restrict__ agg2,
        const float* __restrict__ W2l, const float* __restrict__ b2,
        const float* __restrict__ W2r, const float* __restrict__ Wlin,
        const float* __restrict__ blin, float* __restrict__ out, int N) {
    __shared__ float sa[NPB * 33];
    __shared__ float sh2[NPB * 33];
    __shared__ float swl[32 * 32], swr[32 * 32], swo[64], sb[32], sbo[2];
    int t = threadIdx.x;
    int nb = blockIdx.x * NPB;
    int nn = N - nb; if (nn > NPB) nn = NPB;
    const float4* ga = (const float4*)(agg2 + (size_t)nb * 32);
    const float4* gh = (const float4*)(h + (size_t)nb * 32);
    for (int i = t; i < nn * 8; i += 256) {
        float4 v = ga[i];
        float* d = &sa[(i >> 3) * 33 + (i & 7) * 4];
        d[0] = v.x; d[1] = v.y; d[2] = v.z; d[3] = v.w;
        float4 w = gh[i];
        float* e = &sh2[(i >> 3) * 33 + (i & 7) * 4];
        e[0] = w.x; e[1] = w.y; e[2] = w.z; e[3] = w.w;
    }
    for (int i = t; i < 1024; i += 256) { swl[i] = W2l[i]; swr[i] = W2r[i]; }
    if (t < 64) swo[t] = Wlin[t];
    if (t < 32) sb[t] = b2[t];
    if (t < 2) sbo[t] = blin[t];
    __syncthreads();
    int q2 = t & 3;
    int p = t >> 2;
    int l0 = p * 2, l1 = l0 + 1;
    float acc0[8], acc1[8];
    #pragma unroll
    for (int j = 0; j < 8; ++j) { acc0[j] = sb[q2 * 8 + j]; acc1[j] = acc0[j]; }
    for (int k = 0; k < 32; ++k) {
        float a0 = sa[l0 * 33 + k],  a1 = sa[l1 * 33 + k];
        float h0 = sh2[l0 * 33 + k], h1 = sh2[l1 * 33 + k];
        const float4* wl4 = (const float4*)&swl[k * 32 + q2 * 8];
        const float4* wr4 = (const float4*)&swr[k * 32 + q2 * 8];
        float4 wla = wl4[0], wlb = wl4[1], wra = wr4[0], wrb = wr4[1];
        acc0[0] += a0 * wla.x + h0 * wra.x;  acc1[0] += a1 * wla.x + h1 * wra.x;
        acc0[1] += a0 * wla.y + h0 * wra.y;  acc1[1] += a1 * wla.y + h1 * wra.y;
        acc0[2] += a0 * wla.z + h0 * wra.z;  acc1[2] += a1 * wla.z + h1 * wra.z;
        acc0[3] += a0 * wla.w + h0 * wra.w;  acc1[3] += a1 * wla.w + h1 * wra.w;
        acc0[4] += a0 * wlb.x + h0 * wrb.x;  acc1[4] += a1 * wlb.x + h1 * wrb.x;
        acc0[5] += a0 * wlb.y + h0 * wrb.y;  acc1[5] += a1 * wlb.y + h1 * wrb.y;
        acc0[6] += a0 * wlb.z + h0 * wrb.z;  acc1[6] += a1 * wlb.z + h1 * wrb.z;
        acc0[7] += a0 * wlb.w + h0 * wrb.w;  acc1[7] += a1 * wlb.w + h1 * wrb.w;
    }
    float ss0 = 0.f, ss1 = 0.f;
    #pragma unroll
    for (int j = 0; j < 8; ++j) { ss0 += acc0[j] * acc0[j]; ss1 += acc1[j] * acc1[j]; }
    ss0 += __shfl_xor(ss0, 1); ss0 += __shfl_xor(ss0, 2);
    ss1 += __shfl_xor(ss1, 1); ss1 += __shfl_xor(ss1, 2);
    float inv0 = 1.f / fmaxf(sqrtf(ss0), 1e-12f);
    float inv1 = 1.f / fmaxf(sqrtf(ss1), 1e-12f);
    float o00 = 0.f, o01 = 0.f, o10 = 0.f, o11 = 0.f;
    #pragma unroll
    for (int j = 0; j < 8; ++j) {
        float hv0 = fmaxf(acc0[j] * inv0, 0.f);
        float hv1 = fmaxf(acc1[j] * inv1, 0.f);
        int kk = q2 * 8 + j;
        o00 += hv0 * swo[kk * 2 + 0];
        o01 += hv0 * swo[kk * 2 + 1];
        o10 += hv1 * swo[kk * 2 + 0];
        o11 += hv1 * swo[kk * 2 + 1];
    }
    o00 += __shfl_xor(o00, 1); o00 += __shfl_xor(o00, 2);
    o01 += __shfl_xor(o01, 1); o01 += __shfl_xor(o01, 2);
    o10 += __shfl_xor(o10, 1); o10 += __shfl_xor(o10, 2);
    o11 += __shfl_xor(o11, 1); o11 += __shfl_xor(o11, 2);
    if (q2 == 0) {
        int n0 = nb + l0, n1 = nb + l1;
        if (n0 < N) { out[n0 * 2 + 0] = o00 + sbo[0]; out[n0 * 2 + 1] = o01 + sbo[1]; }
        if (n1 < N) { out[n1 * 2 + 0] = o10 + sbo[0]; out[n1 * 2 + 1] = o11 + sbo[1]; }
    }
}

extern "C" void kernel_launch(void* const* d_in, const int* in_sizes, int n_in,
                              void* d_out, int out_size, void* d_ws, size_t ws_size,
                              hipStream_t stream) {
    const float* x    = (const float*)d_in[0];
    const int*   ei   = (const int*)d_in[1];
    const float* W1l  = (const float*)d_in[2];
    const float* b1   = (const float*)d_in[3];
    const float* W1r  = (const float*)d_in[4];
    const float* W2l  = (const float*)d_in[5];
    const float* b2   = (const float*)d_in[6];
    const float* W2r  = (const float*)d_in[7];
    const float* Wlin = (const float*)d_in[8];
    const float* blin = (const float*)d_in[9];
    float* out = (float*)d_out;

    const int N = in_sizes[0] / 14;
    const int E = in_sizes[1] / 2;
    const int* src = ei;
    const int* dst = ei + E;
    const int NBH = (N + 127) / 128;  // 782 half-buckets
    const int HALF = N / 2;

    char* ws = (char*)d_ws;
    size_t off = 0;
    auto alloc = [&](size_t bytes) -> void* {
        void* p = ws + off;
        off = (off + bytes + 255) & ~(size_t)255;
        return p;
    };
    int*            bcursor    = (int*)alloc((size_t)NBH * 4);
    unsigned*       part       = (unsigned*)alloc((size_t)NBH * CAPH * 4);  // dead after partitionB
    int*            sorted_src = (int*)alloc((size_t)NBH * CAPH * 4);
    int*            deg        = (int*)alloc((size_t)N * 4);
    int*            offs       = (int*)alloc((size_t)N * 4);
    int*            nlo        = (int*)alloc((size_t)N * 4);
    unsigned short* xb         = (unsigned short*)alloc((size_t)N * 16 * 2);
    float*          hbuf       = (float*)alloc((size_t)N * 32 * 4);
    unsigned short* hb         = (unsigned short*)alloc((size_t)N * 32 * 2);
    float*          agg2       = (float*)part;                              // alias dead part buffer
    (void)ws_size; (void)n_in; (void)out_size;

    cvt_x_bf16<<<(N * 16 + 255) / 256, 256, 0, stream>>>(x, xb, bcursor, N, NBH);
    partitionA<<<(E + CHA - 1) / CHA, 1024, 0, stream>>>(src, dst, bcursor, part, E, NBH);
    partitionB_fused<<<NBH, 1024, 0, stream>>>(
        part, bcursor, (const uint4*)xb, x, W1l, b1, W1r,
        deg, offs, nlo, sorted_src, hbuf, hb, N, HALF);
    gather32_p0<<<(N * 4 + 255) / 256, 256, 0, stream>>>(
        (const uint4*)hb, sorted_src, offs, nlo, (float4*)agg2, N);
    gather32_p1<<<(N * 4 + 255) / 256, 256, 0, stream>>>(
        (const uint4*)hb, sorted_src, offs, deg, nlo, (float4*)agg2, N);
    dense2<<<(N + NPB - 1) / NPB, 256, 0, stream>>>(
        hbuf, agg2, W2l, b2, W2r, Wlin, blin, out, N);
}

// Round 15
// 270.179 us; speedup vs baseline: 1.0297x; 1.0114x over previous
//
#include <hip/hip_runtime.h>
#include <hip/hip_bf16.h>

// GraphSAGE (2x SAGEConv mean + normalize + relu, final linear) on MI355X.
// R15: layer-2 gathers deepened to 8 outstanding loads/lane (was 4) — they're
// L2-latency bound, not BW bound. p0/p1 now write independent raw-sum buffers
// (p1 no longer reads p0's output); dense2 merges (a+b)*inv(deg) during its
// coalesced staging loop. Partition pipeline unchanged from R14.

#define CHA 16384   // edges per phase-A block
#define MAXBH 800   // max half-buckets (NBH = ceil(N/128) = 782)
#define CAPH 9728   // slots per 128-node half-bucket region (mean ~8.2K, ~17 sigma)
#define NPB 128     // nodes per dense block

static __device__ __forceinline__ unsigned short f2bf(float f) {
    unsigned u = __float_as_uint(f);
    unsigned r = (u + 0x7FFFu + ((u >> 16) & 1u)) >> 16;   // RTN-even
    return (unsigned short)r;
}
#define BF_LO(u) __uint_as_float((u) << 16)
#define BF_HI(u) __uint_as_float((u) & 0xFFFF0000u)

// x [N x 14] fp32 -> xb [N x 16] bf16 (rows padded to 32B). Also inits bcursor.
__global__ void cvt_x_bf16(const float* __restrict__ x, unsigned short* __restrict__ xb,
                           int* __restrict__ bcursor, int N, int NBH) {
    int idx = blockIdx.x * blockDim.x + threadIdx.x;
    if (idx < NBH) bcursor[idx] = idx * CAPH;
    if (idx >= N * 16) return;
    int n = idx >> 4, f = idx & 15;
    float v = (f < 14) ? x[n * 14 + f] : 0.f;
    xb[idx] = f2bf(v);
}

// Phase A: per-block counting sort into LDS over 782 half-buckets (dst>>7),
// coalesced per-run copy-out. dst/src loaded ONCE as int4 into registers;
// local rank captured from the histogram atomic -> scatter is read+add.
__global__ __launch_bounds__(1024) void partitionA(
        const int* __restrict__ src, const int* __restrict__ dst,
        int* __restrict__ bcursor, unsigned* __restrict__ part, int E, int NBH) {
    __shared__ unsigned pk[CHA];                       // 64 KB staging
    __shared__ int h[MAXBH], lofs[MAXBH], delta[MAXBH];  // 9.4 KB
    int t = threadIdx.x;
    int base = blockIdx.x * CHA;
    int end = base + CHA; if (end > E) end = E;
    int cnt = end - base;

    int ed[16], es[16], er[16];
    for (int i = t; i < NBH; i += 1024) h[i] = 0;
    __syncthreads();
    #pragma unroll
    for (int i = 0; i < 4; ++i) {
        int j = i * 4096 + t * 4;
        if (j + 4 <= cnt) {
            int4 d4 = *(const int4*)(dst + base + j);
            int4 s4 = *(const int4*)(src + base + j);
            ed[i*4+0] = d4.x; ed[i*4+1] = d4.y; ed[i*4+2] = d4.z; ed[i*4+3] = d4.w;
            es[i*4+0] = s4.x; es[i*4+1] = s4.y; es[i*4+2] = s4.z; es[i*4+3] = s4.w;
            er[i*4+0] = atomicAdd(&h[d4.x >> 7], 1);
            er[i*4+1] = atomicAdd(&h[d4.y >> 7], 1);
            er[i*4+2] = atomicAdd(&h[d4.z >> 7], 1);
            er[i*4+3] = atomicAdd(&h[d4.w >> 7], 1);
        } else {
            #pragma unroll
            for (int k = 0; k < 4; ++k) {
                if (j + k < cnt) {
                    ed[i*4+k] = dst[base + j + k];
                    es[i*4+k] = src[base + j + k];
                    er[i*4+k] = atomicAdd(&h[ed[i*4+k] >> 7], 1);
                } else ed[i*4+k] = -1;
            }
        }
    }
    __syncthreads();
    int v = (t < NBH) ? h[t] : 0;
    // in-place Hillis-Steele inclusive scan over h[0..NBH)
    for (int off = 1; off < MAXBH; off <<= 1) {
        int a = 0;
        if (t < NBH && t >= off) a = h[t - off];
        __syncthreads();
        if (t < NBH) h[t] += a;
        __syncthreads();
    }
    if (t < NBH) {
        int excl = h[t] - v;
        lofs[t] = excl;
        int g = v ? atomicAdd(&bcursor[t], v) : 0;   // reserve run in slack region
        delta[t] = g - excl;
    }
    __syncthreads();
    #pragma unroll
    for (int i = 0; i < 16; ++i) {
        int d = ed[i];
        if (d >= 0) {
            int b = d >> 7;
            pk[lofs[b] + er[i]] = ((unsigned)(d & 127) << 24) | (unsigned)es[i];
        }
    }
    __syncthreads();
    // copy-out: h[b] (inclusive scan) is the end of bucket b's run
    int wid = t >> 6, lane = t & 63;
    for (int b = wid; b < NBH; b += 16) {
        int s = lofs[b];
        int e2 = h[b];
        int dlt = delta[b];
        int lim = (b + 1) * CAPH;                    // overflow guard (never hit)
        for (int k = s + lane; k < e2; k += 64) {
            int gidx = dlt + k;
            if (gidx < lim) part[gidx] = pk[k];
        }
    }
}

// Phase B fused, half-bucket: block hb handles 128 dst nodes, reading ONLY its
// own part region. 256-key counting sort (key = dstLocal7*2 + (src>=HALF)),
// ranks captured from the histogram atomics; sorted_src written linearly; then
// fused LAYER-1 GATHER (8 thr/node = 4 edge-streams x 2 row-halves) + DENSE1.
__global__ __launch_bounds__(1024) void partitionB_fused(
        const unsigned* __restrict__ part, const int* __restrict__ bcursor,
        const uint4* __restrict__ xb4, const float* __restrict__ x,
        const float* __restrict__ W1l, const float* __restrict__ b1,
        const float* __restrict__ W1r,
        int* __restrict__ deg, int* __restrict__ offs, int* __restrict__ nlo,
        int* __restrict__ sorted_src, float* __restrict__ hbuf,
        unsigned short* __restrict__ hb, int N, int HALF) {
    __shared__ int pk2[CAPH];                          // 38 KB staging
    __shared__ int hh[256], keyofs[256];
    __shared__ int lstart[128], ldeg[128];
    __shared__ float sagg[128 * 17];                   // agg1 sums, stride 17
    __shared__ float sx[128 * 14];                     // x rows
    __shared__ float swl[448], swr[448], sb1[32];
    __shared__ int sTot;
    int hbid = blockIdx.x;
    int t = threadIdx.x;
    int start = hbid * CAPH;
    int end = bcursor[hbid];
    if (end > start + CAPH) end = start + CAPH;
    int cnt = end - start;
    unsigned ce[10];
    int rk[10];
    if (t < 256) hh[t] = 0;
    if (t >= 512 && t < 960) { swl[t - 512] = W1l[t - 512]; swr[t - 512] = W1r[t - 512]; }
    else if (t >= 960 && t < 992) sb1[t - 960] = b1[t - 960];
    __syncthreads();
    #pragma unroll
    for (int i = 0; i < 10; ++i) {
        int idx = start + t + i * 1024;
        unsigned p = 0xFFFFFFFFu;
        int r = 0;
        if (idx < end) {
            p = part[idx];
            int key = (int)(p >> 24) * 2 + (((int)(p & 0xFFFFFFu) < HALF) ? 0 : 1);
            r = atomicAdd(&hh[key], 1);
        }
        ce[i] = p;
        rk[i] = r;
    }
    {   // stage x rows for this half-bucket
        int nbase = hbid * 128;
        int nnod = N - nbase; if (nnod > 128) nnod = 128; if (nnod < 0) nnod = 0;
        const float* gx = x + (size_t)nbase * 14;
        for (int i = t; i < nnod * 14; i += 1024) sx[i] = gx[i];
    }
    __syncthreads();
    int v = (t < 256) ? hh[t] : 0;
    if (t < 256) keyofs[t] = v;
    __syncthreads();
    // in-place inclusive scan over keyofs
    for (int off = 1; off < 256; off <<= 1) {
        int a2 = (t < 256 && t >= off) ? keyofs[t - off] : 0;
        __syncthreads();
        if (t < 256) keyofs[t] += a2;
        __syncthreads();
    }
    if (t < 256) keyofs[t] -= v;                       // exclusive per key
    if (t == 255) sTot = keyofs[255] + v;
    __syncthreads();
    if (t < 128) {
        int lo = hh[2 * t];
        int d = lo + hh[2 * t + 1];
        int excl = keyofs[2 * t];
        lstart[t] = excl;
        ldeg[t] = d;
        int node = hbid * 128 + t;
        if (node < N) {
            deg[node] = d;
            offs[node] = start + excl;
            nlo[node] = lo;
        }
    }
    __syncthreads();
    #pragma unroll
    for (int i = 0; i < 10; ++i) {
        unsigned p = ce[i];
        if (p != 0xFFFFFFFFu) {
            int s = (int)(p & 0xFFFFFFu);
            int key = (int)(p >> 24) * 2 + ((s < HALF) ? 0 : 1);
            int pos = keyofs[key] + rk[i];
            if (pos < CAPH) pk2[pos] = s;
        }
    }
    __syncthreads();
    int tot = sTot; if (tot > CAPH) tot = CAPH;
    for (int i = t; i < tot; i += 1024)
        sorted_src[start + i] = pk2[i];

    // ---- fused layer-1 gather: 8 threads/node = 4 edge-streams x 2 row-halves
    int node = t >> 3, sub = t & 7, ep = sub >> 1, half = sub & 1;
    int js = lstart[node], d = ldeg[node];
    int je = js + d;
    float a[8] = {0,0,0,0,0,0,0,0};
    int j = js + ep;
    for (; j + 4 < je; j += 8) {                      // 2 edges/iter per stream
        int s0 = pk2[j], s1 = pk2[j + 4];
        uint4 u0 = xb4[s0 * 2 + half], u1 = xb4[s1 * 2 + half];
        a[0] += BF_LO(u0.x) + BF_LO(u1.x);
        a[1] += BF_HI(u0.x) + BF_HI(u1.x);
        a[2] += BF_LO(u0.y) + BF_LO(u1.y);
        a[3] += BF_HI(u0.y) + BF_HI(u1.y);
        a[4] += BF_LO(u0.z) + BF_LO(u1.z);
        a[5] += BF_HI(u0.z) + BF_HI(u1.z);
        a[6] += BF_LO(u0.w) + BF_LO(u1.w);
        a[7] += BF_HI(u0.w) + BF_HI(u1.w);
    }
    for (; j < je; j += 4) {
        uint4 u0 = xb4[pk2[j] * 2 + half];
        a[0] += BF_LO(u0.x); a[1] += BF_HI(u0.x);
        a[2] += BF_LO(u0.y); a[3] += BF_HI(u0.y);
        a[4] += BF_LO(u0.z); a[5] += BF_HI(u0.z);
        a[6] += BF_LO(u0.w); a[7] += BF_HI(u0.w);
    }
    #pragma unroll
    for (int i = 0; i < 8; ++i) {
        a[i] += __shfl_xor(a[i], 2);                  // merge stream pairs
        a[i] += __shfl_xor(a[i], 4);                  // merge all 4 streams
    }
    if (ep == 0) {                                     // sub in {0,1}: both halves
        #pragma unroll
        for (int i = 0; i < 8; ++i) sagg[node * 17 + half * 8 + i] = a[i];
    }
    __syncthreads();

    // ---- fused dense1: 8 threads/node, each computes 4 of 32 outputs
    float inv = 1.0f / ((d > 0) ? (float)d : 1.0f);
    float acc[4];
    #pragma unroll
    for (int i = 0; i < 4; ++i) acc[i] = sb1[sub * 4 + i];
    #pragma unroll
    for (int k = 0; k < 14; ++k) {
        float ag = sagg[node * 17 + k] * inv;
        float xv = sx[node * 14 + k];
        float4 wl = *(const float4*)&swl[k * 32 + sub * 4];
        float4 wr = *(const float4*)&swr[k * 32 + sub * 4];
        acc[0] += ag * wl.x + xv * wr.x;
        acc[1] += ag * wl.y + xv * wr.y;
        acc[2] += ag * wl.z + xv * wr.z;
        acc[3] += ag * wl.w + xv * wr.w;
    }
    float ss = 0.f;
    #pragma unroll
    for (int i = 0; i < 4; ++i) ss += acc[i] * acc[i];
    ss += __shfl_xor(ss, 1); ss += __shfl_xor(ss, 2); ss += __shfl_xor(ss, 4);
    float invn = 1.f / fmaxf(sqrtf(ss), 1e-12f);
    int gnode = hbid * 128 + node;
    if (gnode < N) {
        float hv[4];
        #pragma unroll
        for (int i = 0; i < 4; ++i) hv[i] = fmaxf(acc[i] * invn, 0.f);
        *(float4*)(hbuf + (size_t)gnode * 32 + sub * 4) =
            make_float4(hv[0], hv[1], hv[2], hv[3]);
        uint2 pb;
        pb.x = (unsigned)f2bf(hv[0]) | ((unsigned)f2bf(hv[1]) << 16);
        pb.y = (unsigned)f2bf(hv[2]) | ((unsigned)f2bf(hv[3]) << 16);
        *(uint2*)(hb + (size_t)gnode * 32 + sub * 4) = pb;
    }
}

// Layer-2 gather pass 0 (src < HALF; table half L2-resident): 8-deep unroll,
// writes RAW sums to agg2a (no read-modify-write anywhere).
__global__ __launch_bounds__(256) void gather32_p0(
        const uint4* __restrict__ hb, const int* __restrict__ sorted_src,
        const int* __restrict__ offs, const int* __restrict__ nlo,
        float4* __restrict__ agg2a, int N) {
    int idx = blockIdx.x * blockDim.x + threadIdx.x;
    int n = idx >> 2;
    if (n >= N) return;
    int q = idx & 3;
    int start = offs[n];
    int jend = nlo[n];
    float a0=0,a1=0,a2=0,a3=0,a4=0,a5=0,a6=0,a7=0;
    int j = 0;
    for (; j + 8 <= jend; j += 8) {
        int s0 = sorted_src[start + j + 0];
        int s1 = sorted_src[start + j + 1];
        int s2 = sorted_src[start + j + 2];
        int s3 = sorted_src[start + j + 3];
        int s4 = sorted_src[start + j + 4];
        int s5 = sorted_src[start + j + 5];
        int s6 = sorted_src[start + j + 6];
        int s7 = sorted_src[start + j + 7];
        uint4 u0 = hb[s0 * 4 + q];
        uint4 u1 = hb[s1 * 4 + q];
        uint4 u2 = hb[s2 * 4 + q];
        uint4 u3 = hb[s3 * 4 + q];
        uint4 u4 = hb[s4 * 4 + q];
        uint4 u5 = hb[s5 * 4 + q];
        uint4 u6 = hb[s6 * 4 + q];
        uint4 u7 = hb[s7 * 4 + q];
        a0 += (BF_LO(u0.x)+BF_LO(u1.x)+BF_LO(u2.x)+BF_LO(u3.x))
            + (BF_LO(u4.x)+BF_LO(u5.x)+BF_LO(u6.x)+BF_LO(u7.x));
        a1 += (BF_HI(u0.x)+BF_HI(u1.x)+BF_HI(u2.x)+BF_HI(u3.x))
            + (BF_HI(u4.x)+BF_HI(u5.x)+BF_HI(u6.x)+BF_HI(u7.x));
        a2 += (BF_LO(u0.y)+BF_LO(u1.y)+BF_LO(u2.y)+BF_LO(u3.y))
            + (BF_LO(u4.y)+BF_LO(u5.y)+BF_LO(u6.y)+BF_LO(u7.y));
        a3 += (BF_HI(u0.y)+BF_HI(u1.y)+BF_HI(u2.y)+BF_HI(u3.y))
            + (BF_HI(u4.y)+BF_HI(u5.y)+BF_HI(u6.y)+BF_HI(u7.y));
        a4 += (BF_LO(u0.z)+BF_LO(u1.z)+BF_LO(u2.z)+BF_LO(u3.z))
            + (BF_LO(u4.z)+BF_LO(u5.z)+BF_LO(u6.z)+BF_LO(u7.z));
        a5 += (BF_HI(u0.z)+BF_HI(u1.z)+BF_HI(u2.z)+BF_HI(u3.z))
            + (BF_HI(u4.z)+BF_HI(u5.z)+BF_HI(u6.z)+BF_HI(u7.z));
        a6 += (BF_LO(u0.w)+BF_LO(u1.w)+BF_LO(u2.w)+BF_LO(u3.w))
            + (BF_LO(u4.w)+BF_LO(u5.w)+BF_LO(u6.w)+BF_LO(u7.w));
        a7 += (BF_HI(u0.w)+BF_HI(u1.w)+BF_HI(u2.w)+BF_HI(u3.w))
            + (BF_HI(u4.w)+BF_HI(u5.w)+BF_HI(u6.w)+BF_HI(u7.w));
    }
    for (; j + 4 <= jend; j += 4) {
        int s0 = sorted_src[start + j + 0];
        int s1 = sorted_src[start + j + 1];
        int s2 = sorted_src[start + j + 2];
        int s3 = sorted_src[start + j + 3];
        uint4 u0 = hb[s0 * 4 + q];
        uint4 u1 = hb[s1 * 4 + q];
        uint4 u2 = hb[s2 * 4 + q];
        uint4 u3 = hb[s3 * 4 + q];
        a0 += BF_LO(u0.x)+BF_LO(u1.x)+BF_LO(u2.x)+BF_LO(u3.x);
        a1 += BF_HI(u0.x)+BF_HI(u1.x)+BF_HI(u2.x)+BF_HI(u3.x);
        a2 += BF_LO(u0.y)+BF_LO(u1.y)+BF_LO(u2.y)+BF_LO(u3.y);
        a3 += BF_HI(u0.y)+BF_HI(u1.y)+BF_HI(u2.y)+BF_HI(u3.y);
        a4 += BF_LO(u0.z)+BF_LO(u1.z)+BF_LO(u2.z)+BF_LO(u3.z);
        a5 += BF_HI(u0.z)+BF_HI(u1.z)+BF_HI(u2.z)+BF_HI(u3.z);
        a6 += BF_LO(u0.w)+BF_LO(u1.w)+BF_LO(u2.w)+BF_LO(u3.w);
        a7 += BF_HI(u0.w)+BF_HI(u1.w)+BF_HI(u2.w)+BF_HI(u3.w);
    }
    for (; j < jend; ++j) {
        uint4 u0 = hb[sorted_src[start + j] * 4 + q];
        a0 += BF_LO(u0.x); a1 += BF_HI(u0.x);
        a2 += BF_LO(u0.y); a3 += BF_HI(u0.y);
        a4 += BF_LO(u0.z); a5 += BF_HI(u0.z);
        a6 += BF_LO(u0.w); a7 += BF_HI(u0.w);
    }
    agg2a[n * 8 + q * 2 + 0] = make_float4(a0, a1, a2, a3);
    agg2a[n * 8 + q * 2 + 1] = make_float4(a4, a5, a6, a7);
}

// Layer-2 gather pass 1 (src >= HALF): 8-deep unroll, writes RAW sums to
// agg2b (independent of p0 — no cross-pass data dependency).
__global__ __launch_bounds__(256) void gather32_p1(
        const uint4* __restrict__ hb, const int* __restrict__ sorted_src,
        const int* __restrict__ offs, const int* __restrict__ deg,
        const int* __restrict__ nlo, float4* __restrict__ agg2b, int N) {
    int idx = blockIdx.x * blockDim.x + threadIdx.x;
    int n = idx >> 2;
    if (n >= N) return;
    int q = idx & 3;
    int start = offs[n];
    int d = deg[n];
    int j = nlo[n];
    float a0=0,a1=0,a2=0,a3=0,a4=0,a5=0,a6=0,a7=0;
    for (; j + 8 <= d; j += 8) {
        int s0 = sorted_src[start + j + 0];
        int s1 = sorted_src[start + j + 1];
        int s2 = sorted_src[start + j + 2];
        int s3 = sorted_src[start + j + 3];
        int s4 = sorted_src[start + j + 4];
        int s5 = sorted_src[start + j + 5];
        int s6 = sorted_src[start + j + 6];
        int s7 = sorted_src[start + j + 7];
        uint4 u0 = hb[s0 * 4 + q];
        uint4 u1 = hb[s1 * 4 + q];
        uint4 u2 = hb[s2 * 4 + q];
        uint4 u3 = hb[s3 * 4 + q];
        uint4 u4 = hb[s4 * 4 + q];
        uint4 u5 = hb[s5 * 4 + q];
        uint4 u6 = hb[s6 * 4 + q];
        uint4 u7 = hb[s7 * 4 + q];
        a0 += (BF_LO(u0.x)+BF_LO(u1.x)+BF_LO(u2.x)+BF_LO(u3.x))
            + (BF_LO(u4.x)+BF_LO(u5.x)+BF_LO(u6.x)+BF_LO(u7.x));
        a1 += (BF_HI(u0.x)+BF_HI(u1.x)+BF_HI(u2.x)+BF_HI(u3.x))
            + (BF_HI(u4.x)+BF_HI(u5.x)+BF_HI(u6.x)+BF_HI(u7.x));
        a2 += (BF_LO(u0.y)+BF_LO(u1.y)+BF_LO(u2.y)+BF_LO(u3.y))
            + (BF_LO(u4.y)+BF_LO(u5.y)+BF_LO(u6.y)+BF_LO(u7.y));
        a3 += (BF_HI(u0.y)+BF_HI(u1.y)+BF_HI(u2.y)+BF_HI(u3.y))
            + (BF_HI(u4.y)+BF_HI(u5.y)+BF_HI(u6.y)+BF_HI(u7.y));
        a4 += (BF_LO(u0.z)+BF_LO(u1.z)+BF_LO(u2.z)+BF_LO(u3.z))
            + (BF_LO(u4.z)+BF_LO(u5.z)+BF_LO(u6.z)+BF_LO(u7.z));
        a5 += (BF_HI(u0.z)+BF_HI(u1.z)+BF_HI(u2.z)+BF_HI(u3.z))
            + (BF_HI(u4.z)+BF_HI(u5.z)+BF_HI(u6.z)+BF_HI(u7.z));
        a6 += (BF_LO(u0.w)+BF_LO(u1.w)+BF_LO(u2.w)+BF_LO(u3.w))
            + (BF_LO(u4.w)+BF_LO(u5.w)+BF_LO(u6.w)+BF_LO(u7.w));
        a7 += (BF_HI(u0.w)+BF_HI(u1.w)+BF_HI(u2.w)+BF_HI(u3.w))
            + (BF_HI(u4.w)+BF_HI(u5.w)+BF_HI(u6.w)+BF_HI(u7.w));
    }
    for (; j + 4 <= d; j += 4) {
        int s0 = sorted_src[start + j + 0];
        int s1 = sorted_src[start + j + 1];
        int s2 = sorted_src[start + j + 2];
        int s3 = sorted_src[start + j + 3];
        uint4 u0 = hb[s0 * 4 + q];
        uint4 u1 = hb[s1 * 4 + q];
        uint4 u2 = hb[s2 * 4 + q];
        uint4 u3 = hb[s3 * 4 + q];
        a0 += BF_LO(u0.x)+BF_LO(u1.x)+BF_LO(u2.x)+BF_LO(u3.x);
        a1 += BF_HI(u0.x)+BF_HI(u1.x)+BF_HI(u2.x)+BF_HI(u3.x);
        a2 += BF_LO(u0.y)+BF_LO(u1.y)+BF_LO(u2.y)+BF_LO(u3.y);
        a3 += BF_HI(u0.y)+BF_HI(u1.y)+BF_HI(u2.y)+BF_HI(u3.y);
        a4 += BF_LO(u0.z)+BF_LO(u1.z)+BF_LO(u2.z)+BF_LO(u3.z);
        a5 += BF_HI(u0.z)+BF_HI(u1.z)+BF_HI(u2.z)+BF_HI(u3.z);
        a6 += BF_LO(u0.w)+BF_LO(u1.w)+BF_LO(u2.w)+BF_LO(u3.w);
        a7 += BF_HI(u0.w)+BF_HI(u1.w)+BF_HI(u2.w)+BF_HI(u3.w);
    }
    for (; j < d; ++j) {
        uint4 u0 = hb[sorted_src[start + j] * 4 + q];
        a0 += BF_LO(u0.x); a1 += BF_HI(u0.x);
        a2 += BF_LO(u0.y); a3 += BF_HI(u0.y);
        a4 += BF_LO(u0.z); a5 += BF_HI(u0.z);
        a6 += BF_LO(u0.w); a7 += BF_HI(u0.w);
    }
    agg2b[n * 8 + q * 2 + 0] = make_float4(a0, a1, a2, a3);
    agg2b[n * 8 + q * 2 + 1] = make_float4(a4, a5, a6, a7);
}

// Layer 2 + final linear, tiled. Merges the two raw-sum buffers and applies
// 1/deg during staging (conflict-free padded strides).
__global__ __launch_bounds__(256) void dense2(
        const float* __restrict__ h, const float* __restrict__ agg2a,
        const float* __restrict__ agg2b, const int* __restrict__ deg,
        const float* __restrict__ W2l, const float* __restrict__ b2,
        const float* __restrict__ W2r, const float* __restrict__ Wlin,
        const float* __restrict__ blin, float* __restrict__ out, int N) {
    __shared__ float sa[NPB * 33];
    __shared__ float sh2[NPB * 33];
    __shared__ float swl[32 * 32], swr[32 * 32], swo[64], sb[32], sbo[2];
    int t = threadIdx.x;
    int nb = blockIdx.x * NPB;
    int nn = N - nb; if (nn > NPB) nn = NPB;
    const float4* ga = (const float4*)(agg2a + (size_t)nb * 32);
    const float4* gb = (const float4*)(agg2b + (size_t)nb * 32);
    const float4* gh = (const float4*)(h + (size_t)nb * 32);
    for (int i = t; i < nn * 8; i += 256) {
        int row = i >> 3;
        int dv = deg[nb + row];
        float inv = 1.0f / ((dv > 0) ? (float)dv : 1.0f);
        float4 va = ga[i], vb = gb[i];
        float* d = &sa[row * 33 + (i & 7) * 4];
        d[0] = (va.x + vb.x) * inv; d[1] = (va.y + vb.y) * inv;
        d[2] = (va.z + vb.z) * inv; d[3] = (va.w + vb.w) * inv;
        float4 w = gh[i];
        float* e = &sh2[row * 33 + (i & 7) * 4];
        e[0] = w.x; e[1] = w.y; e[2] = w.z; e[3] = w.w;
    }
    for (int i = t; i < 1024; i += 256) { swl[i] = W2l[i]; swr[i] = W2r[i]; }
    if (t < 64) swo[t] = Wlin[t];
    if (t < 32) sb[t] = b2[t];
    if (t < 2) sbo[t] = blin[t];
    __syncthreads();
    int q2 = t & 3;
    int p = t >> 2;
    int l0 = p * 2, l1 = l0 + 1;
    float acc0[8], acc1[8];
    #pragma unroll
    for (int j = 0; j < 8; ++j) { acc0[j] = sb[q2 * 8 + j]; acc1[j] = acc0[j]; }
    for (int k = 0; k < 32; ++k) {
        float a0 = sa[l0 * 33 + k],  a1 = sa[l1 * 33 + k];
        float h0 = sh2[l0 * 33 + k], h1 = sh2[l1 * 33 + k];
        const float4* wl4 = (const float4*)&swl[k * 32 + q2 * 8];
        const float4* wr4 = (const float4*)&swr[k * 32 + q2 * 8];
        float4 wla = wl4[0], wlb = wl4[1], wra = wr4[0], wrb = wr4[1];
        acc0[0] += a0 * wla.x + h0 * wra.x;  acc1[0] += a1 * wla.x + h1 * wra.x;
        acc0[1] += a0 * wla.y + h0 * wra.y;  acc1[1] += a1 * wla.y + h1 * wra.y;
        acc0[2] += a0 * wla.z + h0 * wra.z;  acc1[2] += a1 * wla.z + h1 * wra.z;
        acc0[3] += a0 * wla.w + h0 * wra.w;  acc1[3] += a1 * wla.w + h1 * wra.w;
        acc0[4] += a0 * wlb.x + h0 * wrb.x;  acc1[4] += a1 * wlb.x + h1 * wrb.x;
        acc0[5] += a0 * wlb.y + h0 * wrb.y;  acc1[5] += a1 * wlb.y + h1 * wrb.y;
        acc0[6] += a0 * wlb.z + h0 * wrb.z;  acc1[6] += a1 * wlb.z + h1 * wrb.z;
        acc0[7] += a0 * wlb.w + h0 * wrb.w;  acc1[7] += a1 * wlb.w + h1 * wrb.w;
    }
    float ss0 = 0.f, ss1 = 0.f;
    #pragma unroll
    for (int j = 0; j < 8; ++j) { ss0 += acc0[j] * acc0[j]; ss1 += acc1[j] * acc1[j]; }
    ss0 += __shfl_xor(ss0, 1); ss0 += __shfl_xor(ss0, 2);
    ss1 += __shfl_xor(ss1, 1); ss1 += __shfl_xor(ss1, 2);
    float inv0 = 1.f / fmaxf(sqrtf(ss0), 1e-12f);
    float inv1 = 1.f / fmaxf(sqrtf(ss1), 1e-12f);
    float o00 = 0.f, o01 = 0.f, o10 = 0.f, o11 = 0.f;
    #pragma unroll
    for (int j = 0; j < 8; ++j) {
        float hv0 = fmaxf(acc0[j] * inv0, 0.f);
        float hv1 = fmaxf(acc1[j] * inv1, 0.f);
        int kk = q2 * 8 + j;
        o00 += hv0 * swo[kk * 2 + 0];
        o01 += hv0 * swo[kk * 2 + 1];
        o10 += hv1 * swo[kk * 2 + 0];
        o11 += hv1 * swo[kk * 2 + 1];
    }
    o00 += __shfl_xor(o00, 1); o00 += __shfl_xor(o00, 2);
    o01 += __shfl_xor(o01, 1); o01 += __shfl_xor(o01, 2);
    o10 += __shfl_xor(o10, 1); o10 += __shfl_xor(o10, 2);
    o11 += __shfl_xor(o11, 1); o11 += __shfl_xor(o11, 2);
    if (q2 == 0) {
        int n0 = nb + l0, n1 = nb + l1;
        if (n0 < N) { out[n0 * 2 + 0] = o00 + sbo[0]; out[n0 * 2 + 1] = o01 + sbo[1]; }
        if (n1 < N) { out[n1 * 2 + 0] = o10 + sbo[0]; out[n1 * 2 + 1] = o11 + sbo[1]; }
    }
}

extern "C" void kernel_launch(void* const* d_in, const int* in_sizes, int n_in,
                              void* d_out, int out_size, void* d_ws, size_t ws_size,
                              hipStream_t stream) {
    const float* x    = (const float*)d_in[0];
    const int*   ei   = (const int*)d_in[1];
    const float* W1l  = (const float*)d_in[2];
    const float* b1   = (const float*)d_in[3];
    const float* W1r  = (const float*)d_in[4];
    const float* W2l  = (const float*)d_in[5];
    const float* b2   = (const float*)d_in[6];
    const float* W2r  = (const float*)d_in[7];
    const float* Wlin = (const float*)d_in[8];
    const float* blin = (const float*)d_in[9];
    float* out = (float*)d_out;

    const int N = in_sizes[0] / 14;
    const int E = in_sizes[1] / 2;
    const int* src = ei;
    const int* dst = ei + E;
    const int NBH = (N + 127) / 128;  // 782 half-buckets
    const int HALF = N / 2;

    char* ws = (char*)d_ws;
    size_t off = 0;
    auto alloc = [&](size_t bytes) -> void* {
        void* p = ws + off;
        off = (off + bytes + 255) & ~(size_t)255;
        return p;
    };
    int*            bcursor    = (int*)alloc((size_t)NBH * 4);
    unsigned*       part       = (unsigned*)alloc((size_t)NBH * CAPH * 4);  // dead after partitionB
    int*            sorted_src = (int*)alloc((size_t)NBH * CAPH * 4);
    int*            deg        = (int*)alloc((size_t)N * 4);
    int*            offs       = (int*)alloc((size_t)N * 4);
    int*            nlo        = (int*)alloc((size_t)N * 4);
    unsigned short* xb         = (unsigned short*)alloc((size_t)N * 16 * 2);
    float*          hbuf       = (float*)alloc((size_t)N * 32 * 4);
    unsigned short* hb         = (unsigned short*)alloc((size_t)N * 32 * 2);
    float*          agg2b      = (float*)alloc((size_t)N * 32 * 4);
    float*          agg2a      = (float*)part;                              // alias dead part buffer
    (void)ws_size; (void)n_in; (void)out_size;

    cvt_x_bf16<<<(N * 16 + 255) / 256, 256, 0, stream>>>(x, xb, bcursor, N, NBH);
    partitionA<<<(E + CHA - 1) / CHA, 1024, 0, stream>>>(src, dst, bcursor, part, E, NBH);
    partitionB_fused<<<NBH, 1024, 0, stream>>>(
        part, bcursor, (const uint4*)xb, x, W1l, b1, W1r,
        deg, offs, nlo, sorted_src, hbuf, hb, N, HALF);
    gather32_p0<<<(N * 4 + 255) / 256, 256, 0, stream>>>(
        (const uint4*)hb, sorted_src, offs, nlo, (float4*)agg2a, N);
    gather32_p1<<<(N * 4 + 255) / 256, 256, 0, stream>>>(
        (const uint4*)hb, sorted_src, offs, deg, nlo, (float4*)agg2b, N);
    dense2<<<(N + NPB - 1) / NPB, 256, 0, stream>>>(
        hbuf, agg2a, agg2b, deg, W2l, b2, W2r, Wlin, blin, out, N);
}